// Round 7
// baseline (1234.963 us; speedup 1.0000x reference)
//
#include <hip/hip_runtime.h>
#include <math.h>

// Problem constants
#define NXg 128
#define NYg 128
#define Pg  (NXg*NYg)      // 16384 pixels
#define Bq  64             // batch
#define Wd  64             // WIDTH (channels)
#define NKX 24             // kept kx rows: 0..11 and 116..127
#define NMODE (NKX*12)     // 288
#define PI2_128 0.04908738521234052f   // 2*pi/128

typedef _Float16 f16x8 __attribute__((ext_vector_type(8)));
typedef _Float16 f16x4 __attribute__((ext_vector_type(4)));
typedef float    f32x4 __attribute__((ext_vector_type(4)));

// ---------------- workspace layout ----------------
// fp32 region (float offsets):
#define OFF_T2C 0
#define OFF_T2S (OFF_T2C + 24*128)
#define OFF_VAL (OFF_T2S + 24*128)
#define OFF_CNT (OFF_VAL + Bq*Pg)
#define OFF_XFR (OFF_CNT + Bq*Pg)
#define OFF_XFI (OFF_XFR + Bq*Wd*NMODE)
#define OFF_OFR (OFF_XFI + Bq*Wd*NMODE)
#define OFF_OFI (OFF_OFR + Bq*Wd*NMODE)
#define F32_END (OFF_OFI + Bq*Wd*NMODE)
// fp16 region (half offsets from (W + F32_END)):
#define H_T1E  0                          // T1e  [t=32][y=128] (0..11 cos, 12..23 -sin, 24..31 zero)
#define H_T1ET (H_T1E + 32*128)           // T1eT [y=128][t=32] transposed copy
#define H_A2   (H_T1ET + 128*32)          // A2   [48][256] stage-B DFT matrix
#define H_PWH  (H_A2 + 48*256)            // PWh  [4][64][64] fp16 pointwise weights
#define H_YG   (H_PWH + 4*64*64)          // Yg   [b][c][x][t=24] fp16, 25 MB
#define H_X    (H_YG + (size_t)Bq*Wd*128*24)  // x [b][x][y][c] fp16, 134 MB

// ---------------- fast gelu: 0.5*v*(1+erf(v/sqrt2)), A&S 7.1.26 erf ----------------
__device__ __forceinline__ float fast_gelu(float v) {
    float a = fabsf(v) * 0.70710678118654752f;   // |v|/sqrt(2)  <-- the R5/R6 bug was missing this scale
    float t = 1.f / (1.f + 0.3275911f * a);
    float p = t * (0.254829592f + t * (-0.284496736f + t * (1.421413741f +
              t * (-1.453152027f + t * 1.061405429f))));
    float er = 1.f - p * __expf(-a * a);
    er = copysignf(er, v);
    return 0.5f * v * (1.f + er);
}

// ---------------- twiddle / weight tables ----------------
__global__ void k_tables(float* T2c, float* T2s, _Float16* T1e_g, _Float16* T1eT_g,
                         _Float16* A2_g, const float* pww, _Float16* PWh) {
    int t = blockIdx.x * blockDim.x + threadIdx.x;   // 0..16383
    if (t < 24*128) {
        int kxi = t >> 7, xx = t & 127;
        int kx = (kxi < 12) ? kxi : (104 + kxi);   // 116..127
        float th = (float)((kx * xx) & 127) * PI2_128;
        T2c[t] = cosf(th);
        T2s[t] = sinf(th);
    }
    if (t < 32*128) {
        int r = t >> 7, y = t & 127;
        float v = 0.f;
        if (r < 12)      v =  cosf((float)((r * y) & 127) * PI2_128);
        else if (r < 24) v = -sinf((float)(((r-12) * y) & 127) * PI2_128);
        T1e_g[t] = (_Float16)v;
        int y2 = t >> 5, r2 = t & 31;
        float v2 = 0.f;
        if (r2 < 12)      v2 =  cosf((float)((r2 * y2) & 127) * PI2_128);
        else if (r2 < 24) v2 = -sinf((float)(((r2-12) * y2) & 127) * PI2_128);
        T1eT_g[t] = (_Float16)v2;
    }
    if (t < 48*256) {
        int m = t >> 8, k = t & 255;
        int x = k & 127;
        int hi = (k >= 128);
        float v;
        if (m < 24) {
            int kx = (m < 12) ? m : (104 + m);
            float th = (float)((kx * x) & 127) * PI2_128;
            v = hi ? sinf(th) : cosf(th);
        } else {
            int mm = m - 24;
            int kx = (mm < 12) ? mm : (104 + mm);
            float th = (float)((kx * x) & 127) * PI2_128;
            v = hi ? cosf(th) : -sinf(th);
        }
        A2_g[t] = (_Float16)v;
    }
    if (t < 4*64*64) PWh[t] = (_Float16)pww[t];
}

// ---------------- sparse scatter ----------------
__global__ void k_scatter(const float* __restrict__ xyt, const float* __restrict__ obs_c,
                          const float* __restrict__ obs_v, const int* __restrict__ nb,
                          const int* __restrict__ siy, const int* __restrict__ six,
                          float* val, float* cnt) {
    int t = blockIdx.x * 64 + threadIdx.x;   // 4096 = B*K
    int b = t >> 6;
    int id = nb[t];
    int sid = id / 50;                       // NT = 50
    float tq = xyt[b*3 + 2];
    float w = expf(-0.1f * fabsf(obs_c[id*3 + 2] - tq));
    int lin = siy[sid] * NYg + six[sid];
    atomicAdd(&val[b*Pg + lin], obs_v[id] * w);
    atomicAdd(&cnt[b*Pg + lin], w);
}

// ---------------- stage-A y-DFT epilogue (shared) ----------------
// Yk[o][t] = sum_y Ot[o][y] * T1e[t][y]; B-fragments straight from L2-hot T1e_g.
__device__ __forceinline__ void stageA(const _Float16 (*Ot)[136], const _Float16* __restrict__ T1e_g,
                                       _Float16* __restrict__ Yg, int b, int row, int tid) {
    int wave = tid >> 6, lane = tid & 63;
    int l15 = lane & 15, quad = lane >> 4;
    f16x8 af[4];
    #pragma unroll
    for (int q = 0; q < 4; q++)
        af[q] = *(const f16x8*)&Ot[wave*16 + l15][q*32 + quad*8];
    #pragma unroll
    for (int nt2 = 0; nt2 < 2; nt2++) {
        f32x4 acc = {0.f,0.f,0.f,0.f};
        #pragma unroll
        for (int q = 0; q < 4; q++) {
            f16x8 bf = *(const f16x8*)&T1e_g[(nt2*16 + l15)*128 + q*32 + quad*8];
            acc = __builtin_amdgcn_mfma_f32_16x16x32_f16(af[q], bf, acc, 0, 0, 0);
        }
        int t = nt2*16 + l15;
        if (t < 24) {
            #pragma unroll
            for (int r = 0; r < 4; r++) {
                int o = wave*16 + quad*4 + r;
                Yg[((size_t)(b*64 + o)*128 + row)*24 + t] = (_Float16)acc[r];
            }
        }
    }
}

// ---------------- fc0 fused with y-DFT ----------------
// grid: (128 rows, Bq), block 256
__global__ __launch_bounds__(256) void k_fc0y(const float* __restrict__ val, const float* __restrict__ cnt,
                      const float* __restrict__ xg, const float* __restrict__ yg,
                      const float* __restrict__ w, const float* __restrict__ bb,
                      const _Float16* __restrict__ T1e_g,
                      _Float16* __restrict__ xh, _Float16* __restrict__ Yg) {
    __shared__ _Float16 Xn[128][72];
    __shared__ _Float16 Ot[64][136];
    __shared__ float gl[128], a1l[128], a2l[128];
    __shared__ float w0[64], w1[64], w2[64], b0[64];
    int row = blockIdx.x, b = blockIdx.y;
    int tid = threadIdx.x;
    if (tid < 128) {
        int p = row*128 + tid;
        float c = cnt[(size_t)b*Pg + p];
        float v = val[(size_t)b*Pg + p];
        gl[tid]  = (c > 0.f) ? v / fmaxf(c, 1e-6f) : 0.f;
        a1l[tid] = xg[p];
        a2l[tid] = yg[p];
    }
    if (tid < 64) {
        w0[tid] = w[tid]; w1[tid] = w[64+tid]; w2[tid] = w[128+tid]; b0[tid] = bb[tid];
    }
    __syncthreads();
    {
        int y = tid & 127, og = tid >> 7;
        float g = gl[y], a1 = a1l[y], a2 = a2l[y];
        #pragma unroll
        for (int blk = 0; blk < 4; blk++) {
            f16x8 pk;
            #pragma unroll
            for (int j = 0; j < 8; j++) {
                int o = og*32 + blk*8 + j;
                float v = g*w0[o] + a1*w1[o] + a2*w2[o] + b0[o];
                _Float16 h = (_Float16)v;
                pk[j] = h;
                Ot[o][y] = h;
            }
            *(f16x8*)&Xn[y][og*32 + blk*8] = pk;
        }
    }
    __syncthreads();
    _Float16* xrow = xh + (size_t)(b*128 + row) * 8192;
    float4* xw4 = (float4*)xrow;
    for (int i = tid; i < 1024; i += 256) {
        int y = i >> 3, seg = i & 7;
        xw4[i] = *(const float4*)&Xn[y][seg*8];
    }
    stageA(Ot, T1e_g, Yg, b, row, tid);
}

// ---------------- sB: stage-B x-DFT (Yg -> xf) via MFMA ----------------
// grid: Bq*Wd, block 256. XF(48m x 12ky) = A2(48x256) @ Ycat(256x12)
__global__ __launch_bounds__(256) void k_sB(const _Float16* __restrict__ Yg,
                    const _Float16* __restrict__ A2_g,
                    float* __restrict__ xfr, float* __restrict__ xfi) {
    __shared__ _Float16 Ys[28][136];   // rows 0..23 valid
    int bc = blockIdx.x;
    int tid = threadIdx.x;
    int wave = tid >> 6, lane = tid & 63;
    int l15 = lane & 15, quad = lane >> 4;
    const _Float16* base = Yg + (size_t)bc * 3072;   // [x][t], t fastest
    for (int i = tid; i < 3072; i += 256) {
        int x = i / 24, t = i - x*24;
        Ys[t][x] = base[i];
    }
    __syncthreads();
    if (wave < 3) {
        f32x4 acc = {0.f,0.f,0.f,0.f};
        #pragma unroll
        for (int q = 0; q < 8; q++) {
            f16x8 a = *(const f16x8*)&A2_g[(size_t)(wave*16 + l15)*256 + q*32 + quad*8];
            const _Float16* brow = (q < 4) ? &Ys[l15][q*32 + quad*8]
                                           : &Ys[12 + l15][(q-4)*32 + quad*8];
            f16x8 bfr = *(const f16x8*)brow;
            acc = __builtin_amdgcn_mfma_f32_16x16x32_f16(a, bfr, acc, 0, 0, 0);
        }
        if (l15 < 12) {
            #pragma unroll
            for (int r = 0; r < 4; r++) {
                int m = wave*16 + quad*4 + r;
                if (m < 24) xfr[(size_t)bc * NMODE + m*12 + l15] = acc[r];
                else        xfi[(size_t)bc * NMODE + (m-24)*12 + l15] = acc[r];
            }
        }
    }
}

// ---------------- S3: mode mixing (complex 64ch -> 64ch), fp32 VALU ----------------
// grid: (Bq, 24), block 256
__global__ __launch_bounds__(256) void k_s3(const float* __restrict__ xfr, const float* __restrict__ xfi,
                    const float* __restrict__ w1r, const float* __restrict__ w1i,
                    const float* __restrict__ w2r, const float* __restrict__ w2i,
                    float* __restrict__ ofr, float* __restrict__ ofi, int layer) {
    __shared__ float ar[64][12], ai[64][12];
    int b = blockIdx.x, kxi = blockIdx.y;
    for (int i = threadIdx.x; i < 64*12; i += 256) {
        int ii = i / 12, ky = i - ii*12;
        size_t idx = (size_t)(b*64 + ii) * NMODE + kxi*12 + ky;
        ar[ii][ky] = xfr[idx];
        ai[ii][ky] = xfi[idx];
    }
    __syncthreads();
    const float *wr, *wi; int kxw;
    if (kxi < 12) { wr = w1r; wi = w1i; kxw = kxi; }
    else          { wr = w2r; wi = w2i; kxw = kxi - 12; }
    size_t lbase = (size_t)layer * 64*64*144 + (size_t)kxw*12;
    for (int o = threadIdx.x; o < 64*12; o += 256) {
        int oo = o / 12, ky = o - oo*12;
        float sr = 0.f, si = 0.f;
        #pragma unroll 4
        for (int i2 = 0; i2 < 64; i2++) {
            float xr = ar[i2][ky], xi2 = ai[i2][ky];
            size_t widx = lbase + (size_t)(i2*64 + oo)*144 + ky;
            float wrr = wr[widx], wii = wi[widx];
            sr += xr*wrr - xi2*wii;
            si += xr*wii + xi2*wrr;
        }
        size_t oidx = (size_t)(b*64 + oo) * NMODE + kxi*12 + ky;
        ofr[oidx] = sr;
        ofi[oidx] = si;
    }
}

// ---------------- S45: inverse-x (VALU) + fused [pointwise | inverse-y] MFMA + gelu + y-DFT
// grid: (128 rows, Bq), block 256 (4 waves). In-place x update; produces next Yg.
__global__ __launch_bounds__(256) void k_s45(_Float16* __restrict__ xh,
                    const float* __restrict__ ofr, const float* __restrict__ ofi,
                    const _Float16* __restrict__ T1e_g, const _Float16* __restrict__ T1eT_g,
                    const _Float16* __restrict__ PWh,
                    const float* __restrict__ T2c, const float* __restrict__ T2s,
                    const float* __restrict__ pwb,
                    _Float16* __restrict__ Yg, int layer) {
    __shared__ _Float16 BsT[128][72];              // x-tile [y][c]
    __shared__ __align__(16) char uni[64*136*2];   // union: As[64][40] then Ot[64][136]
    __shared__ float t2r[24], t2i[24];
    _Float16 (*As)[40]  = (_Float16(*)[40])uni;
    _Float16 (*Ot)[136] = (_Float16(*)[136])uni;

    int row = blockIdx.x, b = blockIdx.y;
    int tid = threadIdx.x;
    int wave = tid >> 6, lane = tid & 63;
    int l15 = lane & 15, quad = lane >> 4;

    _Float16* xrow = xh + (size_t)(b*128 + row) * 8192;

    // x tile: coalesced float4 -> BsT[y][0..63]
    const float4* xr4 = (const float4*)xrow;
    for (int i = tid; i < 1024; i += 256) {
        int y = i >> 3, seg = i & 7;
        *(float4*)&BsT[y][seg*8] = xr4[i];
    }
    // zero As cols 24..31 (cols 32..39 are never read)
    for (int i = tid; i < 512; i += 256)
        As[i >> 3][24 + (i & 7)] = (_Float16)0.f;
    if (tid < 24) {
        t2r[tid] = T2c[tid * 128 + row];
        t2i[tid] = T2s[tid * 128 + row];
    }
    __syncthreads();

    // inverse-x at x=row: G[o][ky] = sum_kx of[o,kx,ky] * e^{+i 2pi kx row/128}
    for (int i = tid; i < 768; i += 256) {
        int o = i / 12, ky = i - o*12;
        const float* pr = ofr + (size_t)(b*64 + o) * NMODE + ky;
        const float* pi = ofi + (size_t)(b*64 + o) * NMODE + ky;
        float sr = 0.f, si = 0.f;
        #pragma unroll
        for (int k = 0; k < 24; k++) {
            float a = pr[k*12], bb = pi[k*12];
            float cc = t2r[k], ss = t2i[k];
            sr += a*cc - bb*ss;
            si += a*ss + bb*cc;
        }
        float sc = ((ky == 0) ? 1.f : 2.f) * (1.f/16384.f);
        As[o][ky]      = (_Float16)(sr * sc);
        As[o][12 + ky] = (_Float16)(si * sc);
    }
    __syncthreads();

    // main GEMM: C[o][y] = W[o][c]@X[c][y] + G'[o][t]@T1eT[y][t]
    f16x8 af0 = *(const f16x8*)&PWh[(size_t)(layer*64 + wave*16 + l15)*64 + quad*8];
    f16x8 af1 = *(const f16x8*)&PWh[(size_t)(layer*64 + wave*16 + l15)*64 + 32 + quad*8];
    f16x8 af2 = *(const f16x8*)&As[wave*16 + l15][quad*8];
    float pb[4];
    #pragma unroll
    for (int r = 0; r < 4; r++)
        pb[r] = pwb[layer*64 + wave*16 + quad*4 + r];
    f32x4 acc[8];
    #pragma unroll
    for (int nt = 0; nt < 8; nt++) {
        f32x4 a = {0.f,0.f,0.f,0.f};
        f16x8 b0 = *(const f16x8*)&BsT[nt*16 + l15][quad*8];
        f16x8 b1 = *(const f16x8*)&BsT[nt*16 + l15][32 + quad*8];
        f16x8 b2 = *(const f16x8*)&T1eT_g[(nt*16 + l15)*32 + quad*8];
        a = __builtin_amdgcn_mfma_f32_16x16x32_f16(af0, b0, a, 0, 0, 0);
        a = __builtin_amdgcn_mfma_f32_16x16x32_f16(af1, b1, a, 0, 0, 0);
        a = __builtin_amdgcn_mfma_f32_16x16x32_f16(af2, b2, a, 0, 0, 0);
        acc[nt] = a;
    }
    __syncthreads();   // BsT/As reads complete before overwrite

    // gelu; write Xn (BsT cols 0..63) packed + Ot
    #pragma unroll
    for (int nt = 0; nt < 8; nt++) {
        int y = nt*16 + l15;
        f16x4 pk;
        #pragma unroll
        for (int r = 0; r < 4; r++) {
            int o = wave*16 + quad*4 + r;
            float v = acc[nt][r] + pb[r];
            _Float16 h = (_Float16)fast_gelu(v);
            pk[r] = h;
            Ot[o][y] = h;
        }
        *(f16x4*)&BsT[y][wave*16 + quad*4] = pk;
    }
    __syncthreads();

    // x store + stage-A
    float4* xw4 = (float4*)xrow;
    for (int i = tid; i < 1024; i += 256) {
        int y = i >> 3, seg = i & 7;
        xw4[i] = *(const float4*)&BsT[y][seg*8];
    }
    stageA(Ot, T1e_g, Yg, b, row, tid);
}

// ---------------- final: layer-3 at 4 points + fc1 + fc2 + bilinear ----------------
// grid: Bq, block 256
__global__ __launch_bounds__(256) void k_final(const _Float16* __restrict__ x,
                    const float* __restrict__ ofr, const float* __restrict__ ofi,
                    const float* __restrict__ pw, const float* __restrict__ pwb,
                    const float* __restrict__ fc1w, const float* __restrict__ fc1b,
                    const float* __restrict__ fc2w, const float* __restrict__ fc2b,
                    const float* __restrict__ xyt, const int* __restrict__ Lx, const int* __restrict__ Ly,
                    float* __restrict__ out) {
    __shared__ float y4[4][64];
    __shared__ float hh[4][129];
    __shared__ int   pxy[4][2];
    __shared__ float wxy[2];
    int b = blockIdx.x;
    if (threadIdx.x == 0) {
        float Lxf = fmaxf((float)Lx[0], 1e-6f);
        float Lyf = fmaxf((float)Ly[0], 1e-6f);
        float x01 = fminf(fmaxf(xyt[b*3 + 0] / Lxf, 0.f), 1.f);
        float y01 = fminf(fmaxf(xyt[b*3 + 1] / Lyf, 0.f), 1.f);
        float gx = x01 * (NXg - 1), gy = y01 * (NYg - 1);
        int x0 = (int)floorf(gx), y0 = (int)floorf(gy);
        int x1 = min(x0 + 1, NXg - 1), y1 = min(y0 + 1, NYg - 1);
        wxy[0] = gx - (float)x0;
        wxy[1] = gy - (float)y0;
        pxy[0][0] = x0; pxy[0][1] = y0;
        pxy[1][0] = x1; pxy[1][1] = y0;
        pxy[2][0] = x0; pxy[2][1] = y1;
        pxy[3][0] = x1; pxy[3][1] = y1;
    }
    __syncthreads();
    {
        int p = threadIdx.x >> 6, o = threadIdx.x & 63;
        int px = pxy[p][0], py = pxy[p][1];
        float gkr[12], gki[12];
        #pragma unroll
        for (int ky = 0; ky < 12; ky++) { gkr[ky] = 0.f; gki[ky] = 0.f; }
        const float* obr = ofr + (size_t)(b*64 + o) * NMODE;
        const float* obi = ofi + (size_t)(b*64 + o) * NMODE;
        for (int kxi = 0; kxi < 24; kxi++) {
            int kx = (kxi < 12) ? kxi : (104 + kxi);
            int m = (kx * px) & 127;
            float th = (float)m * PI2_128;
            float ss, cc; sincosf(th, &ss, &cc);
            #pragma unroll
            for (int ky = 0; ky < 12; ky++) {
                float a = obr[kxi*12 + ky], bb = obi[kxi*12 + ky];
                gkr[ky] += a*cc - bb*ss;
                gki[ky] += a*ss + bb*cc;
            }
        }
        float sp = gkr[0];
        #pragma unroll
        for (int ky = 1; ky < 12; ky++) {
            int m = (ky * py) & 127;
            float th = (float)m * PI2_128;
            float ss, cc; sincosf(th, &ss, &cc);
            sp += 2.f * (gkr[ky]*cc - gki[ky]*ss);
        }
        float s = 0.f;
        const _Float16* xb = x + ((size_t)(b*128 + px)*128 + py)*64;
        #pragma unroll 4
        for (int c = 0; c < 64; c++)
            s += pw[3*4096 + o*64 + c] * (float)xb[c];
        y4[p][o] = sp * (1.f/16384.f) + s + pwb[3*64 + o];
    }
    __syncthreads();
    for (int i = threadIdx.x; i < 512; i += 256) {
        int p = i >> 7, f = i & 127;
        float s = fc1b[f];
        #pragma unroll 4
        for (int w = 0; w < 64; w++) s += y4[p][w] * fc1w[w*128 + f];
        hh[p][f] = 0.5f * s * (1.f + erff(s * 0.70710678118654752f));
    }
    __syncthreads();
    if (threadIdx.x < 3) {
        int o3 = threadIdx.x;
        float f4[4];
        #pragma unroll
        for (int p = 0; p < 4; p++) {
            float s = fc2b[o3];
            #pragma unroll 4
            for (int f = 0; f < 128; f++) s += hh[p][f] * fc2w[f*3 + o3];
            f4[p] = s;
        }
        float wx = wxy[0], wy = wxy[1];
        float top = f4[0]*(1.f - wx) + f4[1]*wx;
        float bot = f4[2]*(1.f - wx) + f4[3]*wx;
        out[b*3 + o3] = top*(1.f - wy) + bot*wy;
    }
}

extern "C" void kernel_launch(void* const* d_in, const int* in_sizes, int n_in,
                              void* d_out, int out_size, void* d_ws, size_t ws_size,
                              hipStream_t stream) {
    const float* xyt    = (const float*)d_in[0];
    const float* obs_c  = (const float*)d_in[1];
    const float* obs_v  = (const float*)d_in[2];
    const float* xg     = (const float*)d_in[3];
    const float* yg     = (const float*)d_in[4];
    const float* fc0w   = (const float*)d_in[5];
    const float* fc0b   = (const float*)d_in[6];
    const float* w1r    = (const float*)d_in[7];
    const float* w1i    = (const float*)d_in[8];
    const float* w2r    = (const float*)d_in[9];
    const float* w2i    = (const float*)d_in[10];
    const float* pww    = (const float*)d_in[11];
    const float* pwb    = (const float*)d_in[12];
    const float* fc1w   = (const float*)d_in[13];
    const float* fc1b   = (const float*)d_in[14];
    const float* fc2w   = (const float*)d_in[15];
    const float* fc2b   = (const float*)d_in[16];
    const int*   nb     = (const int*)d_in[17];
    const int*   siy    = (const int*)d_in[18];
    const int*   six    = (const int*)d_in[19];
    const int*   Lx     = (const int*)d_in[20];
    const int*   Ly     = (const int*)d_in[21];
    float* out = (float*)d_out;

    float* W = (float*)d_ws;
    float* T2c = W + OFF_T2C;
    float* T2s = W + OFF_T2S;
    float* val = W + OFF_VAL;
    float* cnt = W + OFF_CNT;
    float* xfr = W + OFF_XFR;
    float* xfi = W + OFF_XFI;
    float* ofr = W + OFF_OFR;
    float* ofi = W + OFF_OFI;
    _Float16* Hbase = (_Float16*)(W + F32_END);
    _Float16* T1e_g  = Hbase + H_T1E;
    _Float16* T1eT_g = Hbase + H_T1ET;
    _Float16* A2_g   = Hbase + H_A2;
    _Float16* PWh    = Hbase + H_PWH;
    _Float16* Yg     = Hbase + H_YG;
    _Float16* xh     = Hbase + H_X;

    // zero scatter accumulators (val+cnt contiguous)
    hipMemsetAsync(val, 0, (size_t)2 * Bq * Pg * sizeof(float), stream);

    k_tables<<<64, 256, 0, stream>>>(T2c, T2s, T1e_g, T1eT_g, A2_g, pww, PWh);
    k_scatter<<<64, 64, 0, stream>>>(xyt, obs_c, obs_v, nb, siy, six, val, cnt);
    k_fc0y<<<dim3(128, Bq), 256, 0, stream>>>(val, cnt, xg, yg, fc0w, fc0b, T1e_g, xh, Yg);

    for (int l = 0; l < 3; l++) {
        k_sB<<<Bq*Wd, 256, 0, stream>>>(Yg, A2_g, xfr, xfi);
        k_s3<<<dim3(Bq, 24), 256, 0, stream>>>(xfr, xfi, w1r, w1i, w2r, w2i, ofr, ofi, l);
        k_s45<<<dim3(128, Bq), 256, 0, stream>>>(xh, ofr, ofi, T1e_g, T1eT_g, PWh, T2c, T2s, pwb, Yg, l);
    }
    // layer 3: spectral coefficients only; evaluate at 4 points in k_final
    k_sB<<<Bq*Wd, 256, 0, stream>>>(Yg, A2_g, xfr, xfi);
    k_s3<<<dim3(Bq, 24), 256, 0, stream>>>(xfr, xfi, w1r, w1i, w2r, w2i, ofr, ofi, 3);
    k_final<<<Bq, 256, 0, stream>>>(xh, ofr, ofi, pww, pwb, fc1w, fc1b, fc2w, fc2b,
                                    xyt, Lx, Ly, out);
}

// Round 8
// 946.100 us; speedup vs baseline: 1.3053x; 1.3053x over previous
//
#include <hip/hip_runtime.h>
#include <math.h>

// Problem constants
#define NXg 128
#define NYg 128
#define Pg  (NXg*NYg)      // 16384 pixels
#define Bq  64             // batch
#define Wd  64             // WIDTH (channels)
#define NKX 24             // kept kx rows: 0..11 and 116..127
#define NMODE (NKX*12)     // 288
#define PI2_128 0.04908738521234052f   // 2*pi/128

typedef _Float16 f16x8 __attribute__((ext_vector_type(8)));
typedef _Float16 f16x4 __attribute__((ext_vector_type(4)));
typedef float    f32x4 __attribute__((ext_vector_type(4)));

// ---------------- workspace layout ----------------
// fp32 region (float offsets):
#define OFF_XFR 0
#define OFF_XFI (OFF_XFR + Bq*Wd*NMODE)
#define OFF_OFR (OFF_XFI + Bq*Wd*NMODE)
#define OFF_OFI (OFF_OFR + Bq*Wd*NMODE)
#define F32_END (OFF_OFI + Bq*Wd*NMODE)        // 4,718,592 floats ≈ 18.9 MB
// fp16 region (half offsets from (W + F32_END)):
#define H_T1E  0                          // T1e  [t=32][y=128] (0..11 cos, 12..23 -sin, 24..31 zero)
#define H_T1ET (H_T1E + 32*128)           // T1eT [y=128][t=32]
#define H_A2   (H_T1ET + 128*32)          // A2   [48][256] stage-B DFT matrix
#define H_PWH  (H_A2 + 48*256)            // PWh  [4][64][64] fp16 pointwise weights
#define H_T2ET (H_PWH + 4*64*64)          // T2eT [x=128][k=64]: 0..23 cos, 24..47 sin, 48..63 zero
#define H_YG   (H_T2ET + 128*64)          // Yg   [b*c][x][t=24] fp16, 25 MB
#define H_X    (H_YG + (size_t)Bq*Wd*128*24)      // x [b][x][y][c] fp16, 134 MB
#define H_U    (H_X + (size_t)Bq*128*128*64)      // union: val/cnt (8 MB, dies at fc0y) | Gh (25 MB)
// Gh layout: [b][t=24][x=128][o=64] fp16

// ---------------- fast gelu: 0.5*v*(1+erf(v/sqrt2)), A&S 7.1.26 erf ----------------
__device__ __forceinline__ float fast_gelu(float v) {
    float a = fabsf(v) * 0.70710678118654752f;
    float t = 1.f / (1.f + 0.3275911f * a);
    float p = t * (0.254829592f + t * (-0.284496736f + t * (1.421413741f +
              t * (-1.453152027f + t * 1.061405429f))));
    float er = 1.f - p * __expf(-a * a);
    er = copysignf(er, v);
    return 0.5f * v * (1.f + er);
}

// ---------------- twiddle / weight tables ----------------
__global__ void k_tables(_Float16* T1e_g, _Float16* T1eT_g, _Float16* A2_g,
                         const float* pww, _Float16* PWh, _Float16* T2eT_g) {
    int t = blockIdx.x * blockDim.x + threadIdx.x;   // 0..16383
    if (t < 32*128) {
        int r = t >> 7, y = t & 127;
        float v = 0.f;
        if (r < 12)      v =  cosf((float)((r * y) & 127) * PI2_128);
        else if (r < 24) v = -sinf((float)(((r-12) * y) & 127) * PI2_128);
        T1e_g[t] = (_Float16)v;
        int y2 = t >> 5, r2 = t & 31;
        float v2 = 0.f;
        if (r2 < 12)      v2 =  cosf((float)((r2 * y2) & 127) * PI2_128);
        else if (r2 < 24) v2 = -sinf((float)(((r2-12) * y2) & 127) * PI2_128);
        T1eT_g[t] = (_Float16)v2;
    }
    if (t < 48*256) {
        int m = t >> 8, k = t & 255;
        int x = k & 127;
        int hi = (k >= 128);
        float v;
        if (m < 24) {
            int kx = (m < 12) ? m : (104 + m);
            float th = (float)((kx * x) & 127) * PI2_128;
            v = hi ? sinf(th) : cosf(th);
        } else {
            int mm = m - 24;
            int kx = (mm < 12) ? mm : (104 + mm);
            float th = (float)((kx * x) & 127) * PI2_128;
            v = hi ? cosf(th) : -sinf(th);
        }
        A2_g[t] = (_Float16)v;
    }
    if (t < 4*64*64) PWh[t] = (_Float16)pww[t];
    if (t < 128*64) {
        int x = t >> 6, k = t & 63;
        float v = 0.f;
        if (k < 24) {
            int kx = (k < 12) ? k : (104 + k);
            v = cosf((float)((kx * x) & 127) * PI2_128);
        } else if (k < 48) {
            int kk = k - 24;
            int kx = (kk < 12) ? kk : (104 + kk);
            v = sinf((float)((kx * x) & 127) * PI2_128);
        }
        T2eT_g[t] = (_Float16)v;
    }
}

// ---------------- sparse scatter ----------------
__global__ void k_scatter(const float* __restrict__ xyt, const float* __restrict__ obs_c,
                          const float* __restrict__ obs_v, const int* __restrict__ nb,
                          const int* __restrict__ siy, const int* __restrict__ six,
                          float* val, float* cnt) {
    int t = blockIdx.x * 64 + threadIdx.x;   // 4096 = B*K
    int b = t >> 6;
    int id = nb[t];
    int sid = id / 50;                       // NT = 50
    float tq = xyt[b*3 + 2];
    float w = expf(-0.1f * fabsf(obs_c[id*3 + 2] - tq));
    int lin = siy[sid] * NYg + six[sid];
    atomicAdd(&val[b*Pg + lin], obs_v[id] * w);
    atomicAdd(&cnt[b*Pg + lin], w);
}

// ---------------- stage-A y-DFT epilogue (shared) ----------------
__device__ __forceinline__ void stageA(const _Float16 (*Ot)[136], const _Float16* __restrict__ T1e_g,
                                       _Float16* __restrict__ Yg, int b, int row, int tid) {
    int wave = tid >> 6, lane = tid & 63;
    int l15 = lane & 15, quad = lane >> 4;
    // preload all B fragments (L2-hot table), then A frags, then MFMA chain
    f16x8 bf[8];
    #pragma unroll
    for (int u = 0; u < 8; u++) {
        int nt2 = u >> 2, q = u & 3;
        bf[u] = *(const f16x8*)&T1e_g[(nt2*16 + l15)*128 + q*32 + quad*8];
    }
    f16x8 af[4];
    #pragma unroll
    for (int q = 0; q < 4; q++)
        af[q] = *(const f16x8*)&Ot[wave*16 + l15][q*32 + quad*8];
    #pragma unroll
    for (int nt2 = 0; nt2 < 2; nt2++) {
        f32x4 acc = {0.f,0.f,0.f,0.f};
        #pragma unroll
        for (int q = 0; q < 4; q++)
            acc = __builtin_amdgcn_mfma_f32_16x16x32_f16(af[q], bf[nt2*4 + q], acc, 0, 0, 0);
        int t = nt2*16 + l15;
        if (t < 24) {
            #pragma unroll
            for (int r = 0; r < 4; r++) {
                int o = wave*16 + quad*4 + r;
                Yg[((size_t)(b*64 + o)*128 + row)*24 + t] = (_Float16)acc[r];
            }
        }
    }
}

// ---------------- fc0 fused with y-DFT ----------------
// grid: (128 rows, Bq), block 256
__global__ __launch_bounds__(256) void k_fc0y(const float* __restrict__ val, const float* __restrict__ cnt,
                      const float* __restrict__ xg, const float* __restrict__ yg,
                      const float* __restrict__ w, const float* __restrict__ bb,
                      const _Float16* __restrict__ T1e_g,
                      _Float16* __restrict__ xh, _Float16* __restrict__ Yg) {
    __shared__ _Float16 Xn[128][72];
    __shared__ _Float16 Ot[64][136];
    __shared__ float gl[128], a1l[128], a2l[128];
    __shared__ float w0[64], w1[64], w2[64], b0[64];
    int row = blockIdx.x, b = blockIdx.y;
    int tid = threadIdx.x;
    if (tid < 128) {
        int p = row*128 + tid;
        float c = cnt[(size_t)b*Pg + p];
        float v = val[(size_t)b*Pg + p];
        gl[tid]  = (c > 0.f) ? v / fmaxf(c, 1e-6f) : 0.f;
        a1l[tid] = xg[p];
        a2l[tid] = yg[p];
    }
    if (tid < 64) {
        w0[tid] = w[tid]; w1[tid] = w[64+tid]; w2[tid] = w[128+tid]; b0[tid] = bb[tid];
    }
    __syncthreads();
    {
        int y = tid & 127, og = tid >> 7;
        float g = gl[y], a1 = a1l[y], a2 = a2l[y];
        #pragma unroll
        for (int blk = 0; blk < 4; blk++) {
            f16x8 pk;
            #pragma unroll
            for (int j = 0; j < 8; j++) {
                int o = og*32 + blk*8 + j;
                float v = g*w0[o] + a1*w1[o] + a2*w2[o] + b0[o];
                _Float16 h = (_Float16)v;
                pk[j] = h;
                Ot[o][y] = h;
            }
            *(f16x8*)&Xn[y][og*32 + blk*8] = pk;
        }
    }
    __syncthreads();
    _Float16* xrow = xh + (size_t)(b*128 + row) * 8192;
    float4* xw4 = (float4*)xrow;
    for (int i = tid; i < 1024; i += 256) {
        int y = i >> 3, seg = i & 7;
        xw4[i] = *(const float4*)&Xn[y][seg*8];
    }
    stageA(Ot, T1e_g, Yg, b, row, tid);
}

// ---------------- sB: stage-B x-DFT (Yg -> xf) via MFMA ----------------
// grid: Bq*Wd, block 256. XF(48m x 12ky) = A2(48x256) @ Ycat(256x12)
__global__ __launch_bounds__(256) void k_sB(const _Float16* __restrict__ Yg,
                    const _Float16* __restrict__ A2_g,
                    float* __restrict__ xfr, float* __restrict__ xfi) {
    __shared__ _Float16 Ys[28][136];   // rows 0..23 valid
    int bc = blockIdx.x;
    int tid = threadIdx.x;
    int wave = tid >> 6, lane = tid & 63;
    int l15 = lane & 15, quad = lane >> 4;
    const _Float16* base = Yg + (size_t)bc * 3072;   // [x][t], t fastest
    for (int i = tid; i < 3072; i += 256) {
        int x = i / 24, t = i - x*24;
        Ys[t][x] = base[i];
    }
    __syncthreads();
    if (wave < 3) {
        f32x4 acc = {0.f,0.f,0.f,0.f};
        #pragma unroll
        for (int q = 0; q < 8; q++) {
            f16x8 a = *(const f16x8*)&A2_g[(size_t)(wave*16 + l15)*256 + q*32 + quad*8];
            const _Float16* brow = (q < 4) ? &Ys[l15][q*32 + quad*8]
                                           : &Ys[12 + l15][(q-4)*32 + quad*8];
            f16x8 bfr = *(const f16x8*)brow;
            acc = __builtin_amdgcn_mfma_f32_16x16x32_f16(a, bfr, acc, 0, 0, 0);
        }
        if (l15 < 12) {
            #pragma unroll
            for (int r = 0; r < 4; r++) {
                int m = wave*16 + quad*4 + r;
                if (m < 24) xfr[(size_t)bc * NMODE + m*12 + l15] = acc[r];
                else        xfi[(size_t)bc * NMODE + (m-24)*12 + l15] = acc[r];
            }
        }
    }
}

// ---------------- S3: mode mixing (complex 64ch -> 64ch), fp32 VALU ----------------
// grid: (Bq, 24), block 256
__global__ __launch_bounds__(256) void k_s3(const float* __restrict__ xfr, const float* __restrict__ xfi,
                    const float* __restrict__ w1r, const float* __restrict__ w1i,
                    const float* __restrict__ w2r, const float* __restrict__ w2i,
                    float* __restrict__ ofr, float* __restrict__ ofi, int layer) {
    __shared__ float ar[64][12], ai[64][12];
    int b = blockIdx.x, kxi = blockIdx.y;
    for (int i = threadIdx.x; i < 64*12; i += 256) {
        int ii = i / 12, ky = i - ii*12;
        size_t idx = (size_t)(b*64 + ii) * NMODE + kxi*12 + ky;
        ar[ii][ky] = xfr[idx];
        ai[ii][ky] = xfi[idx];
    }
    __syncthreads();
    const float *wr, *wi; int kxw;
    if (kxi < 12) { wr = w1r; wi = w1i; kxw = kxi; }
    else          { wr = w2r; wi = w2i; kxw = kxi - 12; }
    size_t lbase = (size_t)layer * 64*64*144 + (size_t)kxw*12;
    for (int o = threadIdx.x; o < 64*12; o += 256) {
        int oo = o / 12, ky = o - oo*12;
        float sr = 0.f, si = 0.f;
        #pragma unroll 4
        for (int i2 = 0; i2 < 64; i2++) {
            float xr = ar[i2][ky], xi2 = ai[i2][ky];
            size_t widx = lbase + (size_t)(i2*64 + oo)*144 + ky;
            float wrr = wr[widx], wii = wi[widx];
            sr += xr*wrr - xi2*wii;
            si += xr*wii + xi2*wrr;
        }
        size_t oidx = (size_t)(b*64 + oo) * NMODE + kxi*12 + ky;
        ofr[oidx] = sr;
        ofi[oidx] = si;
    }
}

// ---------------- sG: inverse-x as MFMA GEMM: Gh[b][t][x][o] ----------------
// grid: (Bq, 24 t), block 256 (4 waves). Per block: C(64o x 128x) = A(64x48) @ T2e(48x128)
// A rows (t<12, ky=t):  [ sc*ofr | -sc*ofi ];  (t>=12, ky=t-12): [ sc*ofi | sc*ofr ]
__global__ __launch_bounds__(256) void k_sG(const float* __restrict__ ofr, const float* __restrict__ ofi,
                    const _Float16* __restrict__ T2eT_g, _Float16* __restrict__ Gh) {
    __shared__ _Float16 As[64][72];    // [o][k], k 48..63 zero, 64..71 pad
    __shared__ _Float16 Cs[128][72];   // [x][o]
    int b = blockIdx.x, t = blockIdx.y;
    int tid = threadIdx.x;
    int wave = tid >> 6, lane = tid & 63;
    int l15 = lane & 15, quad = lane >> 4;
    int ky = (t < 12) ? t : (t - 12);
    float sc = ((ky == 0) ? 1.f : 2.f) * (1.f/16384.f);
    bool isReal = (t < 12);
    for (int i = tid; i < 1536; i += 256) {
        int o = i / 24, kxi = i - o*24;
        size_t idx = (size_t)(b*64 + o) * NMODE + kxi*12 + ky;
        float vr = ofr[idx] * sc, vi = ofi[idx] * sc;
        As[o][kxi]      = (_Float16)(isReal ? vr : vi);
        As[o][24 + kxi] = (_Float16)(isReal ? -vi : vr);
    }
    for (int i = tid; i < 1024; i += 256)
        As[i >> 4][48 + (i & 15)] = (_Float16)0.f;
    __syncthreads();
    f16x8 a0 = *(const f16x8*)&As[wave*16 + l15][quad*8];
    f16x8 a1 = *(const f16x8*)&As[wave*16 + l15][32 + quad*8];
    #pragma unroll
    for (int nt = 0; nt < 8; nt++) {
        f16x8 b0 = *(const f16x8*)&T2eT_g[(nt*16 + l15)*64 + quad*8];
        f16x8 b1 = *(const f16x8*)&T2eT_g[(nt*16 + l15)*64 + 32 + quad*8];
        f32x4 acc = {0.f,0.f,0.f,0.f};
        acc = __builtin_amdgcn_mfma_f32_16x16x32_f16(a0, b0, acc, 0, 0, 0);
        acc = __builtin_amdgcn_mfma_f32_16x16x32_f16(a1, b1, acc, 0, 0, 0);
        f16x4 pk;
        #pragma unroll
        for (int r = 0; r < 4; r++) pk[r] = (_Float16)acc[r];
        *(f16x4*)&Cs[nt*16 + l15][wave*16 + quad*4] = pk;
    }
    __syncthreads();
    _Float16* outp = Gh + ((size_t)(b*24 + t) << 13);   // [x=128][o=64] flat
    float4* o4 = (float4*)outp;
    for (int i = tid; i < 1024; i += 256) {
        int x = i >> 3, seg = i & 7;
        o4[i] = *(const float4*)&Cs[x][seg*8];
    }
}

// ---------------- S45: fused [pointwise | inverse-y] MFMA + gelu + y-DFT ----------------
// grid: (128 rows, Bq), block 256 (4 waves). In-place x update; produces next Yg.
__global__ __launch_bounds__(256) void k_s45(_Float16* __restrict__ xh,
                    const _Float16* __restrict__ Gh,
                    const _Float16* __restrict__ T1e_g, const _Float16* __restrict__ T1eT_g,
                    const _Float16* __restrict__ PWh,
                    const float* __restrict__ pwb,
                    _Float16* __restrict__ Yg, int layer) {
    __shared__ _Float16 BsT[128][72];   // x-tile [y][c]
    __shared__ _Float16 Ot[64][136];
    int row = blockIdx.x, b = blockIdx.y;
    int tid = threadIdx.x;
    int wave = tid >> 6, lane = tid & 63;
    int l15 = lane & 15, quad = lane >> 4;

    _Float16* xrow = xh + (size_t)(b*128 + row) * 8192;

    // ---- hoisted operand loads (all independent; issue before the fill barrier) ----
    f16x8 af0 = *(const f16x8*)&PWh[(size_t)(layer*64 + wave*16 + l15)*64 + quad*8];
    f16x8 af1 = *(const f16x8*)&PWh[(size_t)(layer*64 + wave*16 + l15)*64 + 32 + quad*8];
    f16x8 af2;
    #pragma unroll
    for (int j = 0; j < 8; j++) af2[j] = (_Float16)0.f;
    if (quad < 3) {
        const _Float16* gbase = Gh + ((size_t)(b*24 + quad*8)*128 + row)*64 + wave*16 + l15;
        #pragma unroll
        for (int j = 0; j < 8; j++) af2[j] = gbase[(size_t)j * 8192];
    }
    f16x8 b2a[8];
    #pragma unroll
    for (int nt = 0; nt < 8; nt++)
        b2a[nt] = *(const f16x8*)&T1eT_g[(nt*16 + l15)*32 + quad*8];
    float pb[4];
    #pragma unroll
    for (int r = 0; r < 4; r++)
        pb[r] = pwb[layer*64 + wave*16 + quad*4 + r];

    // x tile: coalesced float4 -> BsT[y][0..63]
    const float4* xr4 = (const float4*)xrow;
    for (int i = tid; i < 1024; i += 256) {
        int y = i >> 3, seg = i & 7;
        *(float4*)&BsT[y][seg*8] = xr4[i];
    }
    __syncthreads();

    // main GEMM: C[o][y] = W[o][c]@X[c][y] + G'[o][t]@T1eT[y][t]
    f32x4 acc[8];
    #pragma unroll
    for (int nt = 0; nt < 8; nt++) {
        f32x4 a = {0.f,0.f,0.f,0.f};
        f16x8 b0 = *(const f16x8*)&BsT[nt*16 + l15][quad*8];
        f16x8 b1 = *(const f16x8*)&BsT[nt*16 + l15][32 + quad*8];
        a = __builtin_amdgcn_mfma_f32_16x16x32_f16(af0, b0, a, 0, 0, 0);
        a = __builtin_amdgcn_mfma_f32_16x16x32_f16(af1, b1, a, 0, 0, 0);
        a = __builtin_amdgcn_mfma_f32_16x16x32_f16(af2, b2a[nt], a, 0, 0, 0);
        acc[nt] = a;
    }
    __syncthreads();   // BsT reads complete before overwrite

    // gelu; write new activations (BsT cols 0..63) + Ot transpose
    #pragma unroll
    for (int nt = 0; nt < 8; nt++) {
        int y = nt*16 + l15;
        f16x4 pk;
        #pragma unroll
        for (int r = 0; r < 4; r++) {
            int o = wave*16 + quad*4 + r;
            float v = acc[nt][r] + pb[r];
            _Float16 h = (_Float16)fast_gelu(v);
            pk[r] = h;
            Ot[o][y] = h;
        }
        *(f16x4*)&BsT[y][wave*16 + quad*4] = pk;
    }
    __syncthreads();

    // x store + stage-A y-DFT
    float4* xw4 = (float4*)xrow;
    for (int i = tid; i < 1024; i += 256) {
        int y = i >> 3, seg = i & 7;
        xw4[i] = *(const float4*)&BsT[y][seg*8];
    }
    stageA(Ot, T1e_g, Yg, b, row, tid);
}

// ---------------- final: layer-3 at 4 points + fc1 + fc2 + bilinear ----------------
// grid: Bq, block 256
__global__ __launch_bounds__(256) void k_final(const _Float16* __restrict__ x,
                    const float* __restrict__ ofr, const float* __restrict__ ofi,
                    const float* __restrict__ pw, const float* __restrict__ pwb,
                    const float* __restrict__ fc1w, const float* __restrict__ fc1b,
                    const float* __restrict__ fc2w, const float* __restrict__ fc2b,
                    const float* __restrict__ xyt, const int* __restrict__ Lx, const int* __restrict__ Ly,
                    float* __restrict__ out) {
    __shared__ float y4[4][64];
    __shared__ float hh[4][129];
    __shared__ int   pxy[4][2];
    __shared__ float wxy[2];
    int b = blockIdx.x;
    if (threadIdx.x == 0) {
        float Lxf = fmaxf((float)Lx[0], 1e-6f);
        float Lyf = fmaxf((float)Ly[0], 1e-6f);
        float x01 = fminf(fmaxf(xyt[b*3 + 0] / Lxf, 0.f), 1.f);
        float y01 = fminf(fmaxf(xyt[b*3 + 1] / Lyf, 0.f), 1.f);
        float gx = x01 * (NXg - 1), gy = y01 * (NYg - 1);
        int x0 = (int)floorf(gx), y0 = (int)floorf(gy);
        int x1 = min(x0 + 1, NXg - 1), y1 = min(y0 + 1, NYg - 1);
        wxy[0] = gx - (float)x0;
        wxy[1] = gy - (float)y0;
        pxy[0][0] = x0; pxy[0][1] = y0;
        pxy[1][0] = x1; pxy[1][1] = y0;
        pxy[2][0] = x0; pxy[2][1] = y1;
        pxy[3][0] = x1; pxy[3][1] = y1;
    }
    __syncthreads();
    {
        int p = threadIdx.x >> 6, o = threadIdx.x & 63;
        int px = pxy[p][0], py = pxy[p][1];
        float gkr[12], gki[12];
        #pragma unroll
        for (int ky = 0; ky < 12; ky++) { gkr[ky] = 0.f; gki[ky] = 0.f; }
        const float* obr = ofr + (size_t)(b*64 + o) * NMODE;
        const float* obi = ofi + (size_t)(b*64 + o) * NMODE;
        for (int kxi = 0; kxi < 24; kxi++) {
            int kx = (kxi < 12) ? kxi : (104 + kxi);
            int m = (kx * px) & 127;
            float th = (float)m * PI2_128;
            float ss, cc; sincosf(th, &ss, &cc);
            #pragma unroll
            for (int ky = 0; ky < 12; ky++) {
                float a = obr[kxi*12 + ky], bb = obi[kxi*12 + ky];
                gkr[ky] += a*cc - bb*ss;
                gki[ky] += a*ss + bb*cc;
            }
        }
        float sp = gkr[0];
        #pragma unroll
        for (int ky = 1; ky < 12; ky++) {
            int m = (ky * py) & 127;
            float th = (float)m * PI2_128;
            float ss, cc; sincosf(th, &ss, &cc);
            sp += 2.f * (gkr[ky]*cc - gki[ky]*ss);
        }
        float s = 0.f;
        const _Float16* xb = x + ((size_t)(b*128 + px)*128 + py)*64;
        #pragma unroll 4
        for (int c = 0; c < 64; c++)
            s += pw[3*4096 + o*64 + c] * (float)xb[c];
        y4[p][o] = sp * (1.f/16384.f) + s + pwb[3*64 + o];
    }
    __syncthreads();
    for (int i = threadIdx.x; i < 512; i += 256) {
        int p = i >> 7, f = i & 127;
        float s = fc1b[f];
        #pragma unroll 4
        for (int w = 0; w < 64; w++) s += y4[p][w] * fc1w[w*128 + f];
        hh[p][f] = 0.5f * s * (1.f + erff(s * 0.70710678118654752f));
    }
    __syncthreads();
    if (threadIdx.x < 3) {
        int o3 = threadIdx.x;
        float f4[4];
        #pragma unroll
        for (int p = 0; p < 4; p++) {
            float s = fc2b[o3];
            #pragma unroll 4
            for (int f = 0; f < 128; f++) s += hh[p][f] * fc2w[f*3 + o3];
            f4[p] = s;
        }
        float wx = wxy[0], wy = wxy[1];
        float top = f4[0]*(1.f - wx) + f4[1]*wx;
        float bot = f4[2]*(1.f - wx) + f4[3]*wx;
        out[b*3 + o3] = top*(1.f - wy) + bot*wy;
    }
}

extern "C" void kernel_launch(void* const* d_in, const int* in_sizes, int n_in,
                              void* d_out, int out_size, void* d_ws, size_t ws_size,
                              hipStream_t stream) {
    const float* xyt    = (const float*)d_in[0];
    const float* obs_c  = (const float*)d_in[1];
    const float* obs_v  = (const float*)d_in[2];
    const float* xg     = (const float*)d_in[3];
    const float* yg     = (const float*)d_in[4];
    const float* fc0w   = (const float*)d_in[5];
    const float* fc0b   = (const float*)d_in[6];
    const float* w1r    = (const float*)d_in[7];
    const float* w1i    = (const float*)d_in[8];
    const float* w2r    = (const float*)d_in[9];
    const float* w2i    = (const float*)d_in[10];
    const float* pww    = (const float*)d_in[11];
    const float* pwb    = (const float*)d_in[12];
    const float* fc1w   = (const float*)d_in[13];
    const float* fc1b   = (const float*)d_in[14];
    const float* fc2w   = (const float*)d_in[15];
    const float* fc2b   = (const float*)d_in[16];
    const int*   nb     = (const int*)d_in[17];
    const int*   siy    = (const int*)d_in[18];
    const int*   six    = (const int*)d_in[19];
    const int*   Lx     = (const int*)d_in[20];
    const int*   Ly     = (const int*)d_in[21];
    float* out = (float*)d_out;

    float* W = (float*)d_ws;
    float* xfr = W + OFF_XFR;
    float* xfi = W + OFF_XFI;
    float* ofr = W + OFF_OFR;
    float* ofi = W + OFF_OFI;
    _Float16* Hbase = (_Float16*)(W + F32_END);
    _Float16* T1e_g  = Hbase + H_T1E;
    _Float16* T1eT_g = Hbase + H_T1ET;
    _Float16* A2_g   = Hbase + H_A2;
    _Float16* PWh    = Hbase + H_PWH;
    _Float16* T2eT_g = Hbase + H_T2ET;
    _Float16* Yg     = Hbase + H_YG;
    _Float16* xh     = Hbase + H_X;
    // tail union: val/cnt (scatter accumulators, dead after k_fc0y) | Gh (written from layer-0 k_sG on)
    float*    val    = (float*)(Hbase + H_U);
    float*    cnt    = val + Bq*Pg;
    _Float16* Gh     = Hbase + H_U;

    // zero scatter accumulators (val+cnt contiguous)
    hipMemsetAsync(val, 0, (size_t)2 * Bq * Pg * sizeof(float), stream);

    k_tables<<<64, 256, 0, stream>>>(T1e_g, T1eT_g, A2_g, pww, PWh, T2eT_g);
    k_scatter<<<64, 64, 0, stream>>>(xyt, obs_c, obs_v, nb, siy, six, val, cnt);
    k_fc0y<<<dim3(128, Bq), 256, 0, stream>>>(val, cnt, xg, yg, fc0w, fc0b, T1e_g, xh, Yg);

    for (int l = 0; l < 3; l++) {
        k_sB<<<Bq*Wd, 256, 0, stream>>>(Yg, A2_g, xfr, xfi);
        k_s3<<<dim3(Bq, 24), 256, 0, stream>>>(xfr, xfi, w1r, w1i, w2r, w2i, ofr, ofi, l);
        k_sG<<<dim3(Bq, 24), 256, 0, stream>>>(ofr, ofi, T2eT_g, Gh);
        k_s45<<<dim3(128, Bq), 256, 0, stream>>>(xh, Gh, T1e_g, T1eT_g, PWh, pwb, Yg, l);
    }
    // layer 3: spectral coefficients only; evaluate at 4 points in k_final
    k_sB<<<Bq*Wd, 256, 0, stream>>>(Yg, A2_g, xfr, xfi);
    k_s3<<<dim3(Bq, 24), 256, 0, stream>>>(xfr, xfi, w1r, w1i, w2r, w2i, ofr, ofi, 3);
    k_final<<<Bq, 256, 0, stream>>>(xh, ofr, ofi, pww, pwb, fc1w, fc1b, fc2w, fc2b,
                                    xyt, Lx, Ly, out);
}

// Round 9
// 794.384 us; speedup vs baseline: 1.5546x; 1.1910x over previous
//
#include <hip/hip_runtime.h>
#include <math.h>

// Problem constants
#define NXg 128
#define NYg 128
#define Pg  (NXg*NYg)      // 16384 pixels
#define Bq  64             // batch
#define Wd  64             // WIDTH (channels)
#define NKX 24             // kept kx rows: 0..11 and 116..127
#define NMODE (NKX*12)     // 288
#define PI2_128 0.04908738521234052f   // 2*pi/128

typedef _Float16 f16x8 __attribute__((ext_vector_type(8)));
typedef _Float16 f16x4 __attribute__((ext_vector_type(4)));
typedef float    f32x4 __attribute__((ext_vector_type(4)));

// ---------------- workspace layout ----------------
// fp32 region (float offsets): of (layer-3 only, for k_final) + small twiddle tables
#define OFF_OFR 0
#define OFF_OFI (OFF_OFR + Bq*Wd*NMODE)
#define OFF_TC  (OFF_OFI + Bq*Wd*NMODE)
#define OFF_TS  (OFF_TC + 128)
#define F32_END (OFF_TS + 128)
// fp16 region (half offsets from (W + F32_END)):
#define H_T1E  0                          // T1e  [t=32][y=128]
#define H_T1ET (H_T1E + 32*128)           // T1eT [y=128][t=32]
#define H_A2   (H_T1ET + 128*32)          // A2   [48][256]
#define H_PWH  (H_A2 + 48*256)            // PWh  [4][64][64]
#define H_T2ET (H_PWH + 4*64*64)          // T2eT [x=128][k=64]
#define H_XFHR (H_T2ET + 128*64)          // xfh  [mode=288][bc=4096] fp16
#define H_XFHI (H_XFHR + 288*4096)
#define H_OFHR (H_XFHI + 288*4096)        // ofh  [mode][bc] fp16 (layers 0-2)
#define H_OFHI (H_OFHR + 288*4096)
#define H_WHR  (H_OFHI + 288*4096)        // Wh   [3][288][o=64][i=64] fp16
#define H_WHI  (H_WHR + (size_t)3*288*4096)
#define H_YG   (H_WHI + (size_t)3*288*4096)       // Yg [b*c][x][t=24]
#define H_X    (H_YG + (size_t)Bq*Wd*128*24)      // x  [b][x][y][c]
#define H_U    (H_X + (size_t)Bq*128*128*64)      // union: val/cnt | Gh[b][t][x][o]

// ---------------- fast gelu: 0.5*v*(1+erf(v/sqrt2)), A&S 7.1.26 erf ----------------
__device__ __forceinline__ float fast_gelu(float v) {
    float a = fabsf(v) * 0.70710678118654752f;
    float t = 1.f / (1.f + 0.3275911f * a);
    float p = t * (0.254829592f + t * (-0.284496736f + t * (1.421413741f +
              t * (-1.453152027f + t * 1.061405429f))));
    float er = 1.f - p * __expf(-a * a);
    er = copysignf(er, v);
    return 0.5f * v * (1.f + er);
}

// ---------------- prep: tables + scatter + weight transposes, one launch ----------------
// grid 944 blocks x 256: blk<64 tables; 64..79 scatter; 80.. Wh transpose
__global__ void k_prep(_Float16* T1e_g, _Float16* T1eT_g, _Float16* A2_g,
                       const float* pww, _Float16* PWh, _Float16* T2eT_g,
                       float* Tc, float* Ts,
                       const float* xyt, const float* obs_c, const float* obs_v,
                       const int* nb, const int* siy, const int* six,
                       float* val, float* cnt,
                       const float* w1r, const float* w1i,
                       const float* w2r, const float* w2i,
                       _Float16* Whr, _Float16* Whi) {
    int blk = blockIdx.x;
    if (blk < 64) {
        int t = blk * 256 + threadIdx.x;   // 0..16383
        if (t < 32*128) {
            int r = t >> 7, y = t & 127;
            float v = 0.f;
            if (r < 12)      v =  cosf((float)((r * y) & 127) * PI2_128);
            else if (r < 24) v = -sinf((float)(((r-12) * y) & 127) * PI2_128);
            T1e_g[t] = (_Float16)v;
            int y2 = t >> 5, r2 = t & 31;
            float v2 = 0.f;
            if (r2 < 12)      v2 =  cosf((float)((r2 * y2) & 127) * PI2_128);
            else if (r2 < 24) v2 = -sinf((float)(((r2-12) * y2) & 127) * PI2_128);
            T1eT_g[t] = (_Float16)v2;
        }
        if (t < 48*256) {
            int m = t >> 8, k = t & 255;
            int x = k & 127;
            int hi = (k >= 128);
            float v;
            if (m < 24) {
                int kx = (m < 12) ? m : (104 + m);
                float th = (float)((kx * x) & 127) * PI2_128;
                v = hi ? sinf(th) : cosf(th);
            } else {
                int mm = m - 24;
                int kx = (mm < 12) ? mm : (104 + mm);
                float th = (float)((kx * x) & 127) * PI2_128;
                v = hi ? cosf(th) : -sinf(th);
            }
            A2_g[t] = (_Float16)v;
        }
        if (t < 4*64*64) PWh[t] = (_Float16)pww[t];
        if (t < 128*64) {
            int x = t >> 6, k = t & 63;
            float v = 0.f;
            if (k < 24) {
                int kx = (k < 12) ? k : (104 + k);
                v = cosf((float)((kx * x) & 127) * PI2_128);
            } else if (k < 48) {
                int kk = k - 24;
                int kx = (kk < 12) ? kk : (104 + kk);
                v = sinf((float)((kx * x) & 127) * PI2_128);
            }
            T2eT_g[t] = (_Float16)v;
        }
        if (t < 128) {
            float th = (float)t * PI2_128;
            Tc[t] = cosf(th);
            Ts[t] = sinf(th);
        }
    } else if (blk < 80) {
        int t = (blk - 64) * 256 + threadIdx.x;   // 0..4095 = B*K
        int b = t >> 6;
        int id = nb[t];
        int sid = id / 50;                        // NT = 50
        float tq = xyt[b*3 + 2];
        float w = expf(-0.1f * fabsf(obs_c[id*3 + 2] - tq));
        int lin = siy[sid] * NYg + six[sid];
        atomicAdd(&val[b*Pg + lin], obs_v[id] * w);
        atomicAdd(&cnt[b*Pg + lin], w);
    } else {
        // Wh transpose: u in [0, 864): layer 0..2, mode 0..287
        int u = blk - 80;
        int layer = u / 288, mode = u - layer*288;
        int kxi = mode / 12, ky = mode - kxi*12;
        const float *wr, *wi; int kxw;
        if (kxi < 12) { wr = w1r; wi = w1i; kxw = kxi; }
        else          { wr = w2r; wi = w2i; kxw = kxi - 12; }
        size_t obase = (size_t)(layer*288 + mode) * 4096;
        size_t lbase = (size_t)layer * 64*64*144 + (size_t)kxw*12 + ky;
        for (int k = 0; k < 16; k++) {
            int p = k*256 + threadIdx.x;   // p = o*64 + i
            int o = p >> 6, i = p & 63;
            size_t widx = lbase + (size_t)(i*64 + o)*144;
            Whr[obase + p] = (_Float16)wr[widx];
            Whi[obase + p] = (_Float16)wi[widx];
        }
    }
}

// ---------------- stage-A y-DFT epilogue (shared) ----------------
__device__ __forceinline__ void stageA(const _Float16 (*Ot)[140], const _Float16* __restrict__ T1e_g,
                                       _Float16* __restrict__ Yg, int b, int row, int tid) {
    int wave = tid >> 6, lane = tid & 63;
    int l15 = lane & 15, quad = lane >> 4;
    f16x8 bf[8];
    #pragma unroll
    for (int u = 0; u < 8; u++) {
        int nt2 = u >> 2, q = u & 3;
        bf[u] = *(const f16x8*)&T1e_g[(nt2*16 + l15)*128 + q*32 + quad*8];
    }
    f16x8 af[4];
    #pragma unroll
    for (int q = 0; q < 4; q++)
        af[q] = *(const f16x8*)&Ot[wave*16 + l15][q*32 + quad*8];
    #pragma unroll
    for (int nt2 = 0; nt2 < 2; nt2++) {
        f32x4 acc = {0.f,0.f,0.f,0.f};
        #pragma unroll
        for (int q = 0; q < 4; q++)
            acc = __builtin_amdgcn_mfma_f32_16x16x32_f16(af[q], bf[nt2*4 + q], acc, 0, 0, 0);
        int t = nt2*16 + l15;
        if (t < 24) {
            #pragma unroll
            for (int r = 0; r < 4; r++) {
                int o = wave*16 + quad*4 + r;
                Yg[((size_t)(b*64 + o)*128 + row)*24 + t] = (_Float16)acc[r];
            }
        }
    }
}

// ---------------- fc0 fused with y-DFT ----------------
__global__ __launch_bounds__(256) void k_fc0y(const float* __restrict__ val, const float* __restrict__ cnt,
                      const float* __restrict__ xg, const float* __restrict__ yg,
                      const float* __restrict__ w, const float* __restrict__ bb,
                      const _Float16* __restrict__ T1e_g,
                      _Float16* __restrict__ xh, _Float16* __restrict__ Yg) {
    __shared__ _Float16 Xn[128][72];
    __shared__ _Float16 Ot[64][140];
    __shared__ float gl[128], a1l[128], a2l[128];
    __shared__ float w0[64], w1[64], w2[64], b0[64];
    int row = blockIdx.x, b = blockIdx.y;
    int tid = threadIdx.x;
    if (tid < 128) {
        int p = row*128 + tid;
        float c = cnt[(size_t)b*Pg + p];
        float v = val[(size_t)b*Pg + p];
        gl[tid]  = (c > 0.f) ? v / fmaxf(c, 1e-6f) : 0.f;
        a1l[tid] = xg[p];
        a2l[tid] = yg[p];
    }
    if (tid < 64) {
        w0[tid] = w[tid]; w1[tid] = w[64+tid]; w2[tid] = w[128+tid]; b0[tid] = bb[tid];
    }
    __syncthreads();
    {
        int y = tid & 127, og = tid >> 7;
        float g = gl[y], a1 = a1l[y], a2 = a2l[y];
        #pragma unroll
        for (int blk = 0; blk < 4; blk++) {
            f16x8 pk;
            #pragma unroll
            for (int j = 0; j < 8; j++) {
                int o = og*32 + blk*8 + j;
                float v = g*w0[o] + a1*w1[o] + a2*w2[o] + b0[o];
                _Float16 h = (_Float16)v;
                pk[j] = h;
                Ot[o][y] = h;
            }
            *(f16x8*)&Xn[y][og*32 + blk*8] = pk;
        }
    }
    __syncthreads();
    _Float16* xrow = xh + (size_t)(b*128 + row) * 8192;
    float4* xw4 = (float4*)xrow;
    for (int i = tid; i < 1024; i += 256) {
        int y = i >> 3, seg = i & 7;
        xw4[i] = *(const float4*)&Xn[y][seg*8];
    }
    stageA(Ot, T1e_g, Yg, b, row, tid);
}

// ---------------- sB: stage-B x-DFT via MFMA; writes fp16 mode-major xfh ----------------
__global__ __launch_bounds__(256) void k_sB(const _Float16* __restrict__ Yg,
                    const _Float16* __restrict__ A2_g,
                    _Float16* __restrict__ xfhr, _Float16* __restrict__ xfhi) {
    __shared__ _Float16 Ys[28][136];
    int bc = blockIdx.x;
    int tid = threadIdx.x;
    int wave = tid >> 6, lane = tid & 63;
    int l15 = lane & 15, quad = lane >> 4;
    const _Float16* base = Yg + (size_t)bc * 3072;
    for (int i = tid; i < 3072; i += 256) {
        int x = i / 24, t = i - x*24;
        Ys[t][x] = base[i];
    }
    __syncthreads();
    if (wave < 3) {
        f32x4 acc = {0.f,0.f,0.f,0.f};
        #pragma unroll
        for (int q = 0; q < 8; q++) {
            f16x8 a = *(const f16x8*)&A2_g[(size_t)(wave*16 + l15)*256 + q*32 + quad*8];
            const _Float16* brow = (q < 4) ? &Ys[l15][q*32 + quad*8]
                                           : &Ys[12 + l15][(q-4)*32 + quad*8];
            f16x8 bfr = *(const f16x8*)brow;
            acc = __builtin_amdgcn_mfma_f32_16x16x32_f16(a, bfr, acc, 0, 0, 0);
        }
        if (l15 < 12) {
            #pragma unroll
            for (int r = 0; r < 4; r++) {
                int m = wave*16 + quad*4 + r;
                if (m < 24) xfhr[(size_t)(m*12 + l15)*4096 + bc] = (_Float16)acc[r];
                else        xfhi[(size_t)((m-24)*12 + l15)*4096 + bc] = (_Float16)acc[r];
            }
        }
    }
}

// ---------------- s3m: mode mixing via MFMA (layers 0-2) ----------------
// grid 288 (mode), block 256. C[b=64][o=64] complex = X[b][i] @ W[i][o]
__global__ __launch_bounds__(256) void k_s3m(const _Float16* __restrict__ xfhr, const _Float16* __restrict__ xfhi,
                    const _Float16* __restrict__ Whr, const _Float16* __restrict__ Whi,
                    _Float16* __restrict__ ofhr, _Float16* __restrict__ ofhi, int layer) {
    __shared__ _Float16 Xr[64][72], Xi[64][72];
    int mode = blockIdx.x;
    int tid = threadIdx.x;
    int wave = tid >> 6, lane = tid & 63;
    int l15 = lane & 15, quad = lane >> 4;
    const _Float16* pr = xfhr + (size_t)mode * 4096;
    const _Float16* pi = xfhi + (size_t)mode * 4096;
    for (int c8 = tid; c8 < 512; c8 += 256) {
        int b = c8 >> 3, seg = c8 & 7;
        *(f16x8*)&Xr[b][seg*8] = *(const f16x8*)&pr[c8*8];
        *(f16x8*)&Xi[b][seg*8] = *(const f16x8*)&pi[c8*8];
    }
    __syncthreads();
    // B fragments: wave's own o-tile, loop-invariant over m-tiles
    size_t wb = ((size_t)(layer*288 + mode)*64 + wave*16 + l15) * 64 + quad*8;
    f16x8 wr0 = *(const f16x8*)&Whr[wb];
    f16x8 wr1 = *(const f16x8*)&Whr[wb + 32];
    f16x8 wi0 = *(const f16x8*)&Whi[wb];
    f16x8 wi1 = *(const f16x8*)&Whi[wb + 32];
    #pragma unroll
    for (int mt = 0; mt < 4; mt++) {
        f16x8 xr0 = *(const f16x8*)&Xr[mt*16 + l15][quad*8];
        f16x8 xr1 = *(const f16x8*)&Xr[mt*16 + l15][32 + quad*8];
        f16x8 xi0 = *(const f16x8*)&Xi[mt*16 + l15][quad*8];
        f16x8 xi1 = *(const f16x8*)&Xi[mt*16 + l15][32 + quad*8];
        f16x8 xn0, xn1;
        #pragma unroll
        for (int j = 0; j < 8; j++) { xn0[j] = -xi0[j]; xn1[j] = -xi1[j]; }
        f32x4 cr = {0.f,0.f,0.f,0.f}, ci = {0.f,0.f,0.f,0.f};
        cr = __builtin_amdgcn_mfma_f32_16x16x32_f16(xr0, wr0, cr, 0, 0, 0);
        cr = __builtin_amdgcn_mfma_f32_16x16x32_f16(xr1, wr1, cr, 0, 0, 0);
        cr = __builtin_amdgcn_mfma_f32_16x16x32_f16(xn0, wi0, cr, 0, 0, 0);
        cr = __builtin_amdgcn_mfma_f32_16x16x32_f16(xn1, wi1, cr, 0, 0, 0);
        ci = __builtin_amdgcn_mfma_f32_16x16x32_f16(xr0, wi0, ci, 0, 0, 0);
        ci = __builtin_amdgcn_mfma_f32_16x16x32_f16(xr1, wi1, ci, 0, 0, 0);
        ci = __builtin_amdgcn_mfma_f32_16x16x32_f16(xi0, wr0, ci, 0, 0, 0);
        ci = __builtin_amdgcn_mfma_f32_16x16x32_f16(xi1, wr1, ci, 0, 0, 0);
        #pragma unroll
        for (int r = 0; r < 4; r++) {
            int b = mt*16 + quad*4 + r;
            int o = wave*16 + l15;
            ofhr[(size_t)mode*4096 + b*64 + o] = (_Float16)cr[r];
            ofhi[(size_t)mode*4096 + b*64 + o] = (_Float16)ci[r];
        }
    }
}

// ---------------- s3 (fp32 VALU) — layer 3 only, fp32 bc-major output for k_final ------
__global__ __launch_bounds__(256) void k_s3(const _Float16* __restrict__ xfhr, const _Float16* __restrict__ xfhi,
                    const float* __restrict__ w1r, const float* __restrict__ w1i,
                    const float* __restrict__ w2r, const float* __restrict__ w2i,
                    float* __restrict__ ofr, float* __restrict__ ofi, int layer) {
    __shared__ float ar[64][12], ai[64][12];
    int b = blockIdx.x, kxi = blockIdx.y;
    for (int i = threadIdx.x; i < 768; i += 256) {
        int ky = i >> 6, ii = i & 63;
        size_t idx = (size_t)(kxi*12 + ky)*4096 + b*64 + ii;
        ar[ii][ky] = (float)xfhr[idx];
        ai[ii][ky] = (float)xfhi[idx];
    }
    __syncthreads();
    const float *wr, *wi; int kxw;
    if (kxi < 12) { wr = w1r; wi = w1i; kxw = kxi; }
    else          { wr = w2r; wi = w2i; kxw = kxi - 12; }
    size_t lbase = (size_t)layer * 64*64*144 + (size_t)kxw*12;
    for (int o = threadIdx.x; o < 768; o += 256) {
        int oo = o / 12, ky = o - oo*12;
        float sr = 0.f, si = 0.f;
        #pragma unroll 4
        for (int i2 = 0; i2 < 64; i2++) {
            float xr = ar[i2][ky], xi2 = ai[i2][ky];
            size_t widx = lbase + (size_t)(i2*64 + oo)*144 + ky;
            float wrr = wr[widx], wii = wi[widx];
            sr += xr*wrr - xi2*wii;
            si += xr*wii + xi2*wrr;
        }
        size_t oidx = (size_t)(b*64 + oo) * NMODE + kxi*12 + ky;
        ofr[oidx] = sr;
        ofi[oidx] = si;
    }
}

// ---------------- sG: inverse-x as MFMA GEMM: Gh[b][t][x][o], fp16 ofh input ----------
__global__ __launch_bounds__(256) void k_sG(const _Float16* __restrict__ ofhr, const _Float16* __restrict__ ofhi,
                    const _Float16* __restrict__ T2eT_g, _Float16* __restrict__ Gh) {
    __shared__ _Float16 As[64][72];
    __shared__ _Float16 Cs[128][72];
    int b = blockIdx.x, t = blockIdx.y;
    int tid = threadIdx.x;
    int wave = tid >> 6, lane = tid & 63;
    int l15 = lane & 15, quad = lane >> 4;
    int ky = (t < 12) ? t : (t - 12);
    float sc = ((ky == 0) ? 1.f : 2.f) * (1.f/16384.f);
    bool isReal = (t < 12);
    for (int i = tid; i < 1536; i += 256) {
        int kxi = i >> 6, o = i & 63;
        size_t idx = (size_t)(kxi*12 + ky)*4096 + b*64 + o;
        float vr = (float)ofhr[idx] * sc, vi = (float)ofhi[idx] * sc;
        As[o][kxi]      = (_Float16)(isReal ? vr : vi);
        As[o][24 + kxi] = (_Float16)(isReal ? -vi : vr);
    }
    for (int i = tid; i < 1024; i += 256)
        As[i >> 4][48 + (i & 15)] = (_Float16)0.f;
    __syncthreads();
    f16x8 a0 = *(const f16x8*)&As[wave*16 + l15][quad*8];
    f16x8 a1 = *(const f16x8*)&As[wave*16 + l15][32 + quad*8];
    #pragma unroll
    for (int nt = 0; nt < 8; nt++) {
        f16x8 b0 = *(const f16x8*)&T2eT_g[(nt*16 + l15)*64 + quad*8];
        f16x8 b1 = *(const f16x8*)&T2eT_g[(nt*16 + l15)*64 + 32 + quad*8];
        f32x4 acc = {0.f,0.f,0.f,0.f};
        acc = __builtin_amdgcn_mfma_f32_16x16x32_f16(a0, b0, acc, 0, 0, 0);
        acc = __builtin_amdgcn_mfma_f32_16x16x32_f16(a1, b1, acc, 0, 0, 0);
        f16x4 pk;
        #pragma unroll
        for (int r = 0; r < 4; r++) pk[r] = (_Float16)acc[r];
        *(f16x4*)&Cs[nt*16 + l15][wave*16 + quad*4] = pk;
    }
    __syncthreads();
    _Float16* outp = Gh + ((size_t)(b*24 + t) << 13);
    float4* o4 = (float4*)outp;
    for (int i = tid; i < 1024; i += 256) {
        int x = i >> 3, seg = i & 7;
        o4[i] = *(const float4*)&Cs[x][seg*8];
    }
}

// ---------------- S45: fused [pointwise | inverse-y] MFMA + gelu + y-DFT ----------------
__global__ __launch_bounds__(256) void k_s45(_Float16* __restrict__ xh,
                    const _Float16* __restrict__ Gh,
                    const _Float16* __restrict__ T1e_g, const _Float16* __restrict__ T1eT_g,
                    const _Float16* __restrict__ PWh,
                    const float* __restrict__ pwb,
                    _Float16* __restrict__ Yg, int layer,
                    const float* __restrict__ xyt, const int* __restrict__ Lx) {
    __shared__ _Float16 BsT[128][72];
    __shared__ _Float16 Ot[64][140];
    int row = blockIdx.x, b = blockIdx.y;
    int tid = threadIdx.x;
    int wave = tid >> 6, lane = tid & 63;
    int l15 = lane & 15, quad = lane >> 4;

    _Float16* xrow = xh + (size_t)(b*128 + row) * 8192;

    // hoisted operand loads
    f16x8 af0 = *(const f16x8*)&PWh[(size_t)(layer*64 + wave*16 + l15)*64 + quad*8];
    f16x8 af1 = *(const f16x8*)&PWh[(size_t)(layer*64 + wave*16 + l15)*64 + 32 + quad*8];
    f16x8 af2;
    #pragma unroll
    for (int j = 0; j < 8; j++) af2[j] = (_Float16)0.f;
    if (quad < 3) {
        const _Float16* gbase = Gh + ((size_t)(b*24 + quad*8)*128 + row)*64 + wave*16 + l15;
        #pragma unroll
        for (int j = 0; j < 8; j++) af2[j] = gbase[(size_t)j * 8192];
    }
    f16x8 b2a[8];
    #pragma unroll
    for (int nt = 0; nt < 8; nt++)
        b2a[nt] = *(const f16x8*)&T1eT_g[(nt*16 + l15)*32 + quad*8];
    float pb[4];
    #pragma unroll
    for (int r = 0; r < 4; r++)
        pb[r] = pwb[layer*64 + wave*16 + quad*4 + r];

    // x tile fill
    const float4* xr4 = (const float4*)xrow;
    for (int i = tid; i < 1024; i += 256) {
        int y = i >> 3, seg = i & 7;
        *(float4*)&BsT[y][seg*8] = xr4[i];
    }
    __syncthreads();

    f32x4 acc[8];
    #pragma unroll
    for (int nt = 0; nt < 8; nt++) {
        f32x4 a = {0.f,0.f,0.f,0.f};
        f16x8 b0 = *(const f16x8*)&BsT[nt*16 + l15][quad*8];
        f16x8 b1 = *(const f16x8*)&BsT[nt*16 + l15][32 + quad*8];
        a = __builtin_amdgcn_mfma_f32_16x16x32_f16(af0, b0, a, 0, 0, 0);
        a = __builtin_amdgcn_mfma_f32_16x16x32_f16(af1, b1, a, 0, 0, 0);
        a = __builtin_amdgcn_mfma_f32_16x16x32_f16(af2, b2a[nt], a, 0, 0, 0);
        acc[nt] = a;
    }
    __syncthreads();

    #pragma unroll
    for (int nt = 0; nt < 8; nt++) {
        int y = nt*16 + l15;
        f16x4 pk;
        #pragma unroll
        for (int r = 0; r < 4; r++) {
            int o = wave*16 + quad*4 + r;
            float v = acc[nt][r] + pb[r];
            _Float16 h = (_Float16)fast_gelu(v);
            pk[r] = h;
            Ot[o][y] = h;
        }
        *(f16x4*)&BsT[y][wave*16 + quad*4] = pk;
    }
    __syncthreads();

    // x store (layer 2: only the two rows k_final will read)
    bool store_x = true;
    if (layer == 2) {
        float Lxf = fmaxf((float)Lx[0], 1e-6f);
        float x01 = fminf(fmaxf(xyt[b*3 + 0] / Lxf, 0.f), 1.f);
        float gxp = x01 * (NXg - 1);
        int x0 = (int)floorf(gxp);
        int x1 = min(x0 + 1, NXg - 1);
        store_x = (row == x0) || (row == x1);
    }
    if (store_x) {
        float4* xw4 = (float4*)xrow;
        for (int i = tid; i < 1024; i += 256) {
            int y = i >> 3, seg = i & 7;
            xw4[i] = *(const float4*)&BsT[y][seg*8];
        }
    }
    stageA(Ot, T1e_g, Yg, b, row, tid);
}

// ---------------- final ----------------
__global__ __launch_bounds__(256) void k_final(const _Float16* __restrict__ x,
                    const float* __restrict__ ofr, const float* __restrict__ ofi,
                    const float* __restrict__ pw, const float* __restrict__ pwb,
                    const float* __restrict__ fc1w, const float* __restrict__ fc1b,
                    const float* __restrict__ fc2w, const float* __restrict__ fc2b,
                    const float* __restrict__ xyt, const int* __restrict__ Lx, const int* __restrict__ Ly,
                    const float* __restrict__ Tc, const float* __restrict__ Ts,
                    float* __restrict__ out) {
    __shared__ float y4[4][64];
    __shared__ float hh[4][129];
    __shared__ int   pxy[4][2];
    __shared__ float wxy[2];
    __shared__ float tc[128], ts[128];
    int b = blockIdx.x;
    if (threadIdx.x < 128) {
        tc[threadIdx.x] = Tc[threadIdx.x];
        ts[threadIdx.x] = Ts[threadIdx.x];
    }
    if (threadIdx.x == 0) {
        float Lxf = fmaxf((float)Lx[0], 1e-6f);
        float Lyf = fmaxf((float)Ly[0], 1e-6f);
        float x01 = fminf(fmaxf(xyt[b*3 + 0] / Lxf, 0.f), 1.f);
        float y01 = fminf(fmaxf(xyt[b*3 + 1] / Lyf, 0.f), 1.f);
        float gx = x01 * (NXg - 1), gy = y01 * (NYg - 1);
        int x0 = (int)floorf(gx), y0 = (int)floorf(gy);
        int x1 = min(x0 + 1, NXg - 1), y1 = min(y0 + 1, NYg - 1);
        wxy[0] = gx - (float)x0;
        wxy[1] = gy - (float)y0;
        pxy[0][0] = x0; pxy[0][1] = y0;
        pxy[1][0] = x1; pxy[1][1] = y0;
        pxy[2][0] = x0; pxy[2][1] = y1;
        pxy[3][0] = x1; pxy[3][1] = y1;
    }
    __syncthreads();
    {
        int p = threadIdx.x >> 6, o = threadIdx.x & 63;
        int px = pxy[p][0], py = pxy[p][1];
        float gkr[12], gki[12];
        #pragma unroll
        for (int ky = 0; ky < 12; ky++) { gkr[ky] = 0.f; gki[ky] = 0.f; }
        const float* obr = ofr + (size_t)(b*64 + o) * NMODE;
        const float* obi = ofi + (size_t)(b*64 + o) * NMODE;
        for (int kxi = 0; kxi < 24; kxi++) {
            int kx = (kxi < 12) ? kxi : (104 + kxi);
            int m = (kx * px) & 127;
            float cc = tc[m], ss = ts[m];
            #pragma unroll
            for (int ky = 0; ky < 12; ky++) {
                float a = obr[kxi*12 + ky], bb = obi[kxi*12 + ky];
                gkr[ky] += a*cc - bb*ss;
                gki[ky] += a*ss + bb*cc;
            }
        }
        float sp = gkr[0];
        #pragma unroll
        for (int ky = 1; ky < 12; ky++) {
            int m = (ky * py) & 127;
            sp += 2.f * (gkr[ky]*tc[m] - gki[ky]*ts[m]);
        }
        float s = 0.f;
        const _Float16* xb = x + ((size_t)(b*128 + px)*128 + py)*64;
        #pragma unroll 4
        for (int c = 0; c < 64; c++)
            s += pw[3*4096 + o*64 + c] * (float)xb[c];
        y4[p][o] = sp * (1.f/16384.f) + s + pwb[3*64 + o];
    }
    __syncthreads();
    for (int i = threadIdx.x; i < 512; i += 256) {
        int p = i >> 7, f = i & 127;
        float s = fc1b[f];
        #pragma unroll 4
        for (int w = 0; w < 64; w++) s += y4[p][w] * fc1w[w*128 + f];
        hh[p][f] = 0.5f * s * (1.f + erff(s * 0.70710678118654752f));
    }
    __syncthreads();
    if (threadIdx.x < 3) {
        int o3 = threadIdx.x;
        float f4[4];
        #pragma unroll
        for (int p = 0; p < 4; p++) {
            float s = fc2b[o3];
            #pragma unroll 4
            for (int f = 0; f < 128; f++) s += hh[p][f] * fc2w[f*3 + o3];
            f4[p] = s;
        }
        float wx = wxy[0], wy = wxy[1];
        float top = f4[0]*(1.f - wx) + f4[1]*wx;
        float bot = f4[2]*(1.f - wx) + f4[3]*wx;
        out[b*3 + o3] = top*(1.f - wy) + bot*wy;
    }
}

extern "C" void kernel_launch(void* const* d_in, const int* in_sizes, int n_in,
                              void* d_out, int out_size, void* d_ws, size_t ws_size,
                              hipStream_t stream) {
    const float* xyt    = (const float*)d_in[0];
    const float* obs_c  = (const float*)d_in[1];
    const float* obs_v  = (const float*)d_in[2];
    const float* xg     = (const float*)d_in[3];
    const float* yg     = (const float*)d_in[4];
    const float* fc0w   = (const float*)d_in[5];
    const float* fc0b   = (const float*)d_in[6];
    const float* w1r    = (const float*)d_in[7];
    const float* w1i    = (const float*)d_in[8];
    const float* w2r    = (const float*)d_in[9];
    const float* w2i    = (const float*)d_in[10];
    const float* pww    = (const float*)d_in[11];
    const float* pwb    = (const float*)d_in[12];
    const float* fc1w   = (const float*)d_in[13];
    const float* fc1b   = (const float*)d_in[14];
    const float* fc2w   = (const float*)d_in[15];
    const float* fc2b   = (const float*)d_in[16];
    const int*   nb     = (const int*)d_in[17];
    const int*   siy    = (const int*)d_in[18];
    const int*   six    = (const int*)d_in[19];
    const int*   Lx     = (const int*)d_in[20];
    const int*   Ly     = (const int*)d_in[21];
    float* out = (float*)d_out;

    float* W = (float*)d_ws;
    float* ofr = W + OFF_OFR;
    float* ofi = W + OFF_OFI;
    float* Tc  = W + OFF_TC;
    float* Ts  = W + OFF_TS;
    _Float16* Hbase = (_Float16*)(W + F32_END);
    _Float16* T1e_g  = Hbase + H_T1E;
    _Float16* T1eT_g = Hbase + H_T1ET;
    _Float16* A2_g   = Hbase + H_A2;
    _Float16* PWh    = Hbase + H_PWH;
    _Float16* T2eT_g = Hbase + H_T2ET;
    _Float16* xfhr   = Hbase + H_XFHR;
    _Float16* xfhi   = Hbase + H_XFHI;
    _Float16* ofhr   = Hbase + H_OFHR;
    _Float16* ofhi   = Hbase + H_OFHI;
    _Float16* Whr    = Hbase + H_WHR;
    _Float16* Whi    = Hbase + H_WHI;
    _Float16* Yg     = Hbase + H_YG;
    _Float16* xh     = Hbase + H_X;
    float*    val    = (float*)(Hbase + H_U);
    float*    cnt    = val + Bq*Pg;
    _Float16* Gh     = Hbase + H_U;

    hipMemsetAsync(val, 0, (size_t)2 * Bq * Pg * sizeof(float), stream);

    k_prep<<<944, 256, 0, stream>>>(T1e_g, T1eT_g, A2_g, pww, PWh, T2eT_g, Tc, Ts,
                                    xyt, obs_c, obs_v, nb, siy, six, val, cnt,
                                    w1r, w1i, w2r, w2i, Whr, Whi);
    k_fc0y<<<dim3(128, Bq), 256, 0, stream>>>(val, cnt, xg, yg, fc0w, fc0b, T1e_g, xh, Yg);

    for (int l = 0; l < 3; l++) {
        k_sB<<<Bq*Wd, 256, 0, stream>>>(Yg, A2_g, xfhr, xfhi);
        k_s3m<<<288, 256, 0, stream>>>(xfhr, xfhi, Whr, Whi, ofhr, ofhi, l);
        k_sG<<<dim3(Bq, 24), 256, 0, stream>>>(ofhr, ofhi, T2eT_g, Gh);
        k_s45<<<dim3(128, Bq), 256, 0, stream>>>(xh, Gh, T1e_g, T1eT_g, PWh, pwb, Yg, l, xyt, Lx);
    }
    // layer 3: spectral coefficients (fp32 path) + k_final
    k_sB<<<Bq*Wd, 256, 0, stream>>>(Yg, A2_g, xfhr, xfhi);
    k_s3<<<dim3(Bq, 24), 256, 0, stream>>>(xfhr, xfhi, w1r, w1i, w2r, w2i, ofr, ofi, 3);
    k_final<<<Bq, 256, 0, stream>>>(xh, ofr, ofi, pww, pwb, fc1w, fc1b, fc2w, fc2b,
                                    xyt, Lx, Ly, Tc, Ts, out);
}

// Round 10
// 747.952 us; speedup vs baseline: 1.6511x; 1.0621x over previous
//
#include <hip/hip_runtime.h>
#include <math.h>

// Problem constants
#define NXg 128
#define NYg 128
#define Pg  (NXg*NYg)      // 16384 pixels
#define Bq  64             // batch
#define Wd  64             // WIDTH (channels)
#define NKX 24             // kept kx rows: 0..11 and 116..127
#define NMODE (NKX*12)     // 288
#define PI2_128 0.04908738521234052f   // 2*pi/128

typedef _Float16 f16x8 __attribute__((ext_vector_type(8)));
typedef _Float16 f16x4 __attribute__((ext_vector_type(4)));
typedef float    f32x4 __attribute__((ext_vector_type(4)));

// ---------------- workspace layout ----------------
// fp32 region (float offsets): just the 128-entry twiddle tables for k_final
#define OFF_TC  0
#define OFF_TS  (OFF_TC + 128)
#define F32_END (OFF_TS + 128)
// fp16 region (half offsets from (W + F32_END)):
#define H_T1E  0                          // T1e  [t=32][y=128]
#define H_T1ET (H_T1E + 32*128)           // T1eT [y=128][t=32]
#define H_A2   (H_T1ET + 128*32)          // A2   [48][256]
#define H_PWH  (H_A2 + 48*256)            // PWh  [4][64][64]
#define H_T2ET (H_PWH + 4*64*64)          // T2eT [x=128][k=64]
#define H_XFHR (H_T2ET + 128*64)          // xfh  [mode=288][bc=4096] fp16
#define H_XFHI (H_XFHR + 288*4096)
#define H_OFHR (H_XFHI + 288*4096)        // ofh  [mode][bc] fp16 (all 4 layers; layer3 read by k_final)
#define H_OFHI (H_OFHR + 288*4096)
#define H_WHR  (H_OFHI + 288*4096)        // Wh   [4][288][o=64][i=64] fp16
#define H_WHI  (H_WHR + (size_t)4*288*4096)
#define H_YG   (H_WHI + (size_t)4*288*4096)       // Yg [b*c][x][t=24]
#define H_X    (H_YG + (size_t)Bq*Wd*128*24)      // x  [b][x][y][c]
#define H_U    (H_X + (size_t)Bq*128*128*64)      // union: val/cnt | Gh[b][t][x][o]

// ---------------- fast gelu: 0.5*v*(1+erf(v/sqrt2)), A&S 7.1.26 erf ----------------
__device__ __forceinline__ float fast_gelu(float v) {
    float a = fabsf(v) * 0.70710678118654752f;
    float t = 1.f / (1.f + 0.3275911f * a);
    float p = t * (0.254829592f + t * (-0.284496736f + t * (1.421413741f +
              t * (-1.453152027f + t * 1.061405429f))));
    float er = 1.f - p * __expf(-a * a);
    er = copysignf(er, v);
    return 0.5f * v * (1.f + er);
}

// ---------------- prep: tables + scatter + weight transposes (4 layers), one launch ----
// grid 1232 blocks x 256: blk<64 tables; 64..79 scatter; 80..1231 Wh transpose
__global__ void k_prep(_Float16* T1e_g, _Float16* T1eT_g, _Float16* A2_g,
                       const float* pww, _Float16* PWh, _Float16* T2eT_g,
                       float* Tc, float* Ts,
                       const float* xyt, const float* obs_c, const float* obs_v,
                       const int* nb, const int* siy, const int* six,
                       float* val, float* cnt,
                       const float* w1r, const float* w1i,
                       const float* w2r, const float* w2i,
                       _Float16* Whr, _Float16* Whi) {
    int blk = blockIdx.x;
    if (blk < 64) {
        int t = blk * 256 + threadIdx.x;   // 0..16383
        if (t < 32*128) {
            int r = t >> 7, y = t & 127;
            float v = 0.f;
            if (r < 12)      v =  cosf((float)((r * y) & 127) * PI2_128);
            else if (r < 24) v = -sinf((float)(((r-12) * y) & 127) * PI2_128);
            T1e_g[t] = (_Float16)v;
            int y2 = t >> 5, r2 = t & 31;
            float v2 = 0.f;
            if (r2 < 12)      v2 =  cosf((float)((r2 * y2) & 127) * PI2_128);
            else if (r2 < 24) v2 = -sinf((float)(((r2-12) * y2) & 127) * PI2_128);
            T1eT_g[t] = (_Float16)v2;
        }
        if (t < 48*256) {
            int m = t >> 8, k = t & 255;
            int x = k & 127;
            int hi = (k >= 128);
            float v;
            if (m < 24) {
                int kx = (m < 12) ? m : (104 + m);
                float th = (float)((kx * x) & 127) * PI2_128;
                v = hi ? sinf(th) : cosf(th);
            } else {
                int mm = m - 24;
                int kx = (mm < 12) ? mm : (104 + mm);
                float th = (float)((kx * x) & 127) * PI2_128;
                v = hi ? cosf(th) : -sinf(th);
            }
            A2_g[t] = (_Float16)v;
        }
        if (t < 4*64*64) PWh[t] = (_Float16)pww[t];
        if (t < 128*64) {
            int x = t >> 6, k = t & 63;
            float v = 0.f;
            if (k < 24) {
                int kx = (k < 12) ? k : (104 + k);
                v = cosf((float)((kx * x) & 127) * PI2_128);
            } else if (k < 48) {
                int kk = k - 24;
                int kx = (kk < 12) ? kk : (104 + kk);
                v = sinf((float)((kx * x) & 127) * PI2_128);
            }
            T2eT_g[t] = (_Float16)v;
        }
        if (t < 128) {
            float th = (float)t * PI2_128;
            Tc[t] = cosf(th);
            Ts[t] = sinf(th);
        }
    } else if (blk < 80) {
        int t = (blk - 64) * 256 + threadIdx.x;   // 0..4095 = B*K
        int b = t >> 6;
        int id = nb[t];
        int sid = id / 50;                        // NT = 50
        float tq = xyt[b*3 + 2];
        float w = expf(-0.1f * fabsf(obs_c[id*3 + 2] - tq));
        int lin = siy[sid] * NYg + six[sid];
        atomicAdd(&val[b*Pg + lin], obs_v[id] * w);
        atomicAdd(&cnt[b*Pg + lin], w);
    } else {
        // Wh transpose: u in [0, 1152): layer 0..3, mode 0..287
        int u = blk - 80;
        int layer = u / 288, mode = u - layer*288;
        int kxi = mode / 12, ky = mode - kxi*12;
        const float *wr, *wi; int kxw;
        if (kxi < 12) { wr = w1r; wi = w1i; kxw = kxi; }
        else          { wr = w2r; wi = w2i; kxw = kxi - 12; }
        size_t obase = (size_t)(layer*288 + mode) * 4096;
        size_t lbase = (size_t)layer * 64*64*144 + (size_t)kxw*12 + ky;
        for (int k = 0; k < 16; k++) {
            int p = k*256 + threadIdx.x;   // p = o*64 + i
            int o = p >> 6, i = p & 63;
            size_t widx = lbase + (size_t)(i*64 + o)*144;
            Whr[obase + p] = (_Float16)wr[widx];
            Whi[obase + p] = (_Float16)wi[widx];
        }
    }
}

// ---------------- stage-A y-DFT epilogue (shared) ----------------
// Yk[o][t] = sum_y Xn[y][o] * T1e[t][y]; A-frags via scalar column reads of Xn.
__device__ __forceinline__ void stageA(const _Float16 (*Xn)[76], const _Float16* __restrict__ T1e_g,
                                       _Float16* __restrict__ Yg, int b, int row, int tid) {
    int wave = tid >> 6, lane = tid & 63;
    int l15 = lane & 15, quad = lane >> 4;
    f16x8 bf[8];
    #pragma unroll
    for (int u = 0; u < 8; u++) {
        int nt2 = u >> 2, q = u & 3;
        bf[u] = *(const f16x8*)&T1e_g[(nt2*16 + l15)*128 + q*32 + quad*8];
    }
    f16x8 af[4];
    #pragma unroll
    for (int q = 0; q < 4; q++)
        #pragma unroll
        for (int j = 0; j < 8; j++)
            af[q][j] = Xn[q*32 + quad*8 + j][wave*16 + l15];
    #pragma unroll
    for (int nt2 = 0; nt2 < 2; nt2++) {
        f32x4 acc = {0.f,0.f,0.f,0.f};
        #pragma unroll
        for (int q = 0; q < 4; q++)
            acc = __builtin_amdgcn_mfma_f32_16x16x32_f16(af[q], bf[nt2*4 + q], acc, 0, 0, 0);
        int t = nt2*16 + l15;
        if (t < 24) {
            #pragma unroll
            for (int r = 0; r < 4; r++) {
                int o = wave*16 + quad*4 + r;
                Yg[((size_t)(b*64 + o)*128 + row)*24 + t] = (_Float16)acc[r];
            }
        }
    }
}

// ---------------- fc0-lite: compute fc0 + stage-A only (no x store) ----------------
// grid: (128 rows, Bq), block 256
__global__ __launch_bounds__(256) void k_fc0y(const float* __restrict__ val, const float* __restrict__ cnt,
                      const float* __restrict__ xg, const float* __restrict__ yg,
                      const float* __restrict__ w, const float* __restrict__ bb,
                      const _Float16* __restrict__ T1e_g,
                      _Float16* __restrict__ Yg) {
    __shared__ _Float16 Xn[128][76];
    __shared__ float wl[4][64];
    int row = blockIdx.x, b = blockIdx.y;
    int tid = threadIdx.x;
    if (tid < 64) {
        wl[0][tid] = w[tid]; wl[1][tid] = w[64+tid]; wl[2][tid] = w[128+tid]; wl[3][tid] = bb[tid];
    }
    __syncthreads();
    {
        int y = tid & 127, half = tid >> 7;
        int p = row*128 + y;
        float c = cnt[(size_t)b*Pg + p];
        float g = (c > 0.f) ? val[(size_t)b*Pg + p] / fmaxf(c, 1e-6f) : 0.f;
        float a1 = xg[p], a2 = yg[p];
        #pragma unroll
        for (int blk = 0; blk < 4; blk++) {
            f16x8 pk;
            #pragma unroll
            for (int j = 0; j < 8; j++) {
                int o = half*32 + blk*8 + j;
                pk[j] = (_Float16)(g*wl[0][o] + a1*wl[1][o] + a2*wl[2][o] + wl[3][o]);
            }
            *(f16x8*)&Xn[y][half*32 + blk*8] = pk;
        }
    }
    __syncthreads();
    stageA(Xn, T1e_g, Yg, b, row, tid);
}

// ---------------- sB: stage-B x-DFT via MFMA; writes fp16 mode-major xfh ----------------
__global__ __launch_bounds__(256) void k_sB(const _Float16* __restrict__ Yg,
                    const _Float16* __restrict__ A2_g,
                    _Float16* __restrict__ xfhr, _Float16* __restrict__ xfhi) {
    __shared__ _Float16 Ys[28][136];
    int bc = blockIdx.x;
    int tid = threadIdx.x;
    int wave = tid >> 6, lane = tid & 63;
    int l15 = lane & 15, quad = lane >> 4;
    const _Float16* base = Yg + (size_t)bc * 3072;
    for (int i = tid; i < 3072; i += 256) {
        int x = i / 24, t = i - x*24;
        Ys[t][x] = base[i];
    }
    __syncthreads();
    if (wave < 3) {
        f32x4 acc = {0.f,0.f,0.f,0.f};
        #pragma unroll
        for (int q = 0; q < 8; q++) {
            f16x8 a = *(const f16x8*)&A2_g[(size_t)(wave*16 + l15)*256 + q*32 + quad*8];
            const _Float16* brow = (q < 4) ? &Ys[l15][q*32 + quad*8]
                                           : &Ys[12 + l15][(q-4)*32 + quad*8];
            f16x8 bfr = *(const f16x8*)brow;
            acc = __builtin_amdgcn_mfma_f32_16x16x32_f16(a, bfr, acc, 0, 0, 0);
        }
        if (l15 < 12) {
            #pragma unroll
            for (int r = 0; r < 4; r++) {
                int m = wave*16 + quad*4 + r;
                if (m < 24) xfhr[(size_t)(m*12 + l15)*4096 + bc] = (_Float16)acc[r];
                else        xfhi[(size_t)((m-24)*12 + l15)*4096 + bc] = (_Float16)acc[r];
            }
        }
    }
}

// ---------------- s3m: mode mixing via MFMA (all 4 layers) ----------------
// grid 288 (mode), block 256. C[b=64][o=64] complex = X[b][i] @ W[i][o]
__global__ __launch_bounds__(256) void k_s3m(const _Float16* __restrict__ xfhr, const _Float16* __restrict__ xfhi,
                    const _Float16* __restrict__ Whr, const _Float16* __restrict__ Whi,
                    _Float16* __restrict__ ofhr, _Float16* __restrict__ ofhi, int layer) {
    __shared__ _Float16 Xr[64][72], Xi[64][72];
    int mode = blockIdx.x;
    int tid = threadIdx.x;
    int wave = tid >> 6, lane = tid & 63;
    int l15 = lane & 15, quad = lane >> 4;
    const _Float16* pr = xfhr + (size_t)mode * 4096;
    const _Float16* pi = xfhi + (size_t)mode * 4096;
    for (int c8 = tid; c8 < 512; c8 += 256) {
        int b = c8 >> 3, seg = c8 & 7;
        *(f16x8*)&Xr[b][seg*8] = *(const f16x8*)&pr[c8*8];
        *(f16x8*)&Xi[b][seg*8] = *(const f16x8*)&pi[c8*8];
    }
    __syncthreads();
    size_t wb = ((size_t)(layer*288 + mode)*64 + wave*16 + l15) * 64 + quad*8;
    f16x8 wr0 = *(const f16x8*)&Whr[wb];
    f16x8 wr1 = *(const f16x8*)&Whr[wb + 32];
    f16x8 wi0 = *(const f16x8*)&Whi[wb];
    f16x8 wi1 = *(const f16x8*)&Whi[wb + 32];
    #pragma unroll
    for (int mt = 0; mt < 4; mt++) {
        f16x8 xr0 = *(const f16x8*)&Xr[mt*16 + l15][quad*8];
        f16x8 xr1 = *(const f16x8*)&Xr[mt*16 + l15][32 + quad*8];
        f16x8 xi0 = *(const f16x8*)&Xi[mt*16 + l15][quad*8];
        f16x8 xi1 = *(const f16x8*)&Xi[mt*16 + l15][32 + quad*8];
        f16x8 xn0, xn1;
        #pragma unroll
        for (int j = 0; j < 8; j++) { xn0[j] = -xi0[j]; xn1[j] = -xi1[j]; }
        f32x4 cr = {0.f,0.f,0.f,0.f}, ci = {0.f,0.f,0.f,0.f};
        cr = __builtin_amdgcn_mfma_f32_16x16x32_f16(xr0, wr0, cr, 0, 0, 0);
        cr = __builtin_amdgcn_mfma_f32_16x16x32_f16(xr1, wr1, cr, 0, 0, 0);
        cr = __builtin_amdgcn_mfma_f32_16x16x32_f16(xn0, wi0, cr, 0, 0, 0);
        cr = __builtin_amdgcn_mfma_f32_16x16x32_f16(xn1, wi1, cr, 0, 0, 0);
        ci = __builtin_amdgcn_mfma_f32_16x16x32_f16(xr0, wi0, ci, 0, 0, 0);
        ci = __builtin_amdgcn_mfma_f32_16x16x32_f16(xr1, wi1, ci, 0, 0, 0);
        ci = __builtin_amdgcn_mfma_f32_16x16x32_f16(xi0, wr0, ci, 0, 0, 0);
        ci = __builtin_amdgcn_mfma_f32_16x16x32_f16(xi1, wr1, ci, 0, 0, 0);
        #pragma unroll
        for (int r = 0; r < 4; r++) {
            int b = mt*16 + quad*4 + r;
            int o = wave*16 + l15;
            ofhr[(size_t)mode*4096 + b*64 + o] = (_Float16)cr[r];
            ofhi[(size_t)mode*4096 + b*64 + o] = (_Float16)ci[r];
        }
    }
}

// ---------------- sG: inverse-x as MFMA GEMM: Gh[b][t][x][o] ----------------
__global__ __launch_bounds__(256) void k_sG(const _Float16* __restrict__ ofhr, const _Float16* __restrict__ ofhi,
                    const _Float16* __restrict__ T2eT_g, _Float16* __restrict__ Gh) {
    __shared__ _Float16 As[64][72];
    __shared__ _Float16 Cs[128][72];
    int b = blockIdx.x, t = blockIdx.y;
    int tid = threadIdx.x;
    int wave = tid >> 6, lane = tid & 63;
    int l15 = lane & 15, quad = lane >> 4;
    int ky = (t < 12) ? t : (t - 12);
    float sc = ((ky == 0) ? 1.f : 2.f) * (1.f/16384.f);
    bool isReal = (t < 12);
    for (int i = tid; i < 1536; i += 256) {
        int kxi = i >> 6, o = i & 63;
        size_t idx = (size_t)(kxi*12 + ky)*4096 + b*64 + o;
        float vr = (float)ofhr[idx] * sc, vi = (float)ofhi[idx] * sc;
        As[o][kxi]      = (_Float16)(isReal ? vr : vi);
        As[o][24 + kxi] = (_Float16)(isReal ? -vi : vr);
    }
    for (int i = tid; i < 1024; i += 256)
        As[i >> 4][48 + (i & 15)] = (_Float16)0.f;
    __syncthreads();
    f16x8 a0 = *(const f16x8*)&As[wave*16 + l15][quad*8];
    f16x8 a1 = *(const f16x8*)&As[wave*16 + l15][32 + quad*8];
    #pragma unroll
    for (int nt = 0; nt < 8; nt++) {
        f16x8 b0 = *(const f16x8*)&T2eT_g[(nt*16 + l15)*64 + quad*8];
        f16x8 b1 = *(const f16x8*)&T2eT_g[(nt*16 + l15)*64 + 32 + quad*8];
        f32x4 acc = {0.f,0.f,0.f,0.f};
        acc = __builtin_amdgcn_mfma_f32_16x16x32_f16(a0, b0, acc, 0, 0, 0);
        acc = __builtin_amdgcn_mfma_f32_16x16x32_f16(a1, b1, acc, 0, 0, 0);
        f16x4 pk;
        #pragma unroll
        for (int r = 0; r < 4; r++) pk[r] = (_Float16)acc[r];
        *(f16x4*)&Cs[nt*16 + l15][wave*16 + quad*4] = pk;
    }
    __syncthreads();
    _Float16* outp = Gh + ((size_t)(b*24 + t) << 13);
    float4* o4 = (float4*)outp;
    for (int i = tid; i < 1024; i += 256) {
        int x = i >> 3, seg = i & 7;
        o4[i] = *(const float4*)&Cs[x][seg*8];
    }
}

// ---------------- S45: fused [pointwise | inverse-y] MFMA + gelu + y-DFT ----------------
// layer 0 recomputes fc0 inline (x never stored by fc0y).
__global__ __launch_bounds__(256) void k_s45(_Float16* __restrict__ xh,
                    const _Float16* __restrict__ Gh,
                    const _Float16* __restrict__ T1e_g, const _Float16* __restrict__ T1eT_g,
                    const _Float16* __restrict__ PWh,
                    const float* __restrict__ pwb,
                    _Float16* __restrict__ Yg, int layer,
                    const float* __restrict__ xyt, const int* __restrict__ Lx,
                    const float* __restrict__ val, const float* __restrict__ cnt,
                    const float* __restrict__ xg, const float* __restrict__ yg,
                    const float* __restrict__ fc0w, const float* __restrict__ fc0b) {
    __shared__ _Float16 BsT[128][76];   // [y][c]; also holds post-gelu output
    __shared__ float wl[4][64];
    int row = blockIdx.x, b = blockIdx.y;
    int tid = threadIdx.x;
    int wave = tid >> 6, lane = tid & 63;
    int l15 = lane & 15, quad = lane >> 4;

    _Float16* xrow = xh + (size_t)(b*128 + row) * 8192;

    // hoisted operand loads
    f16x8 af0 = *(const f16x8*)&PWh[(size_t)(layer*64 + wave*16 + l15)*64 + quad*8];
    f16x8 af1 = *(const f16x8*)&PWh[(size_t)(layer*64 + wave*16 + l15)*64 + 32 + quad*8];
    f16x8 af2;
    #pragma unroll
    for (int j = 0; j < 8; j++) af2[j] = (_Float16)0.f;
    if (quad < 3) {
        const _Float16* gbase = Gh + ((size_t)(b*24 + quad*8)*128 + row)*64 + wave*16 + l15;
        #pragma unroll
        for (int j = 0; j < 8; j++) af2[j] = gbase[(size_t)j * 8192];
    }
    f16x8 b2a[8];
    #pragma unroll
    for (int nt = 0; nt < 8; nt++)
        b2a[nt] = *(const f16x8*)&T1eT_g[(nt*16 + l15)*32 + quad*8];
    float pb[4];
    #pragma unroll
    for (int r = 0; r < 4; r++)
        pb[r] = pwb[layer*64 + wave*16 + quad*4 + r];

    // x tile fill: layer 0 recomputes fc0; others load from xh
    if (layer == 0) {
        if (tid < 64) {
            wl[0][tid] = fc0w[tid]; wl[1][tid] = fc0w[64+tid];
            wl[2][tid] = fc0w[128+tid]; wl[3][tid] = fc0b[tid];
        }
        __syncthreads();
        int y = tid & 127, half = tid >> 7;
        int p = row*128 + y;
        float c = cnt[(size_t)b*Pg + p];
        float g = (c > 0.f) ? val[(size_t)b*Pg + p] / fmaxf(c, 1e-6f) : 0.f;
        float a1 = xg[p], a2 = yg[p];
        #pragma unroll
        for (int blk = 0; blk < 4; blk++) {
            f16x8 pk;
            #pragma unroll
            for (int j = 0; j < 8; j++) {
                int o = half*32 + blk*8 + j;
                pk[j] = (_Float16)(g*wl[0][o] + a1*wl[1][o] + a2*wl[2][o] + wl[3][o]);
            }
            *(f16x8*)&BsT[y][half*32 + blk*8] = pk;
        }
    } else {
        const float4* xr4 = (const float4*)xrow;
        for (int i = tid; i < 1024; i += 256) {
            int y = i >> 3, seg = i & 7;
            *(float4*)&BsT[y][seg*8] = xr4[i];
        }
    }
    __syncthreads();

    // main GEMM: C[o][y] = W[o][c]@X[c][y] + G'[o][t]@T1eT[y][t]
    f32x4 acc[8];
    #pragma unroll
    for (int nt = 0; nt < 8; nt++) {
        f32x4 a = {0.f,0.f,0.f,0.f};
        f16x8 b0 = *(const f16x8*)&BsT[nt*16 + l15][quad*8];
        f16x8 b1 = *(const f16x8*)&BsT[nt*16 + l15][32 + quad*8];
        a = __builtin_amdgcn_mfma_f32_16x16x32_f16(af0, b0, a, 0, 0, 0);
        a = __builtin_amdgcn_mfma_f32_16x16x32_f16(af1, b1, a, 0, 0, 0);
        a = __builtin_amdgcn_mfma_f32_16x16x32_f16(af2, b2a[nt], a, 0, 0, 0);
        acc[nt] = a;
    }
    __syncthreads();   // BsT reads complete before overwrite

    // gelu; write new activations back into BsT cols 0..63
    #pragma unroll
    for (int nt = 0; nt < 8; nt++) {
        int y = nt*16 + l15;
        f16x4 pk;
        #pragma unroll
        for (int r = 0; r < 4; r++) {
            float v = acc[nt][r] + pb[r];
            pk[r] = (_Float16)fast_gelu(v);
        }
        *(f16x4*)&BsT[y][wave*16 + quad*4] = pk;
    }
    __syncthreads();

    // x store (layer 2: only the two rows k_final will read)
    bool store_x = true;
    if (layer == 2) {
        float Lxf = fmaxf((float)Lx[0], 1e-6f);
        float x01 = fminf(fmaxf(xyt[b*3 + 0] / Lxf, 0.f), 1.f);
        float gxp = x01 * (NXg - 1);
        int x0 = (int)floorf(gxp);
        int x1 = min(x0 + 1, NXg - 1);
        store_x = (row == x0) || (row == x1);
    }
    if (store_x) {
        float4* xw4 = (float4*)xrow;
        for (int i = tid; i < 1024; i += 256) {
            int y = i >> 3, seg = i & 7;
            xw4[i] = *(const float4*)&BsT[y][seg*8];
        }
    }
    stageA(BsT, T1e_g, Yg, b, row, tid);
}

// ---------------- final: layer-3 at 4 points + fc1 + fc2 + bilinear ----------------
__global__ __launch_bounds__(256) void k_final(const _Float16* __restrict__ x,
                    const _Float16* __restrict__ ofhr, const _Float16* __restrict__ ofhi,
                    const float* __restrict__ pw, const float* __restrict__ pwb,
                    const float* __restrict__ fc1w, const float* __restrict__ fc1b,
                    const float* __restrict__ fc2w, const float* __restrict__ fc2b,
                    const float* __restrict__ xyt, const int* __restrict__ Lx, const int* __restrict__ Ly,
                    const float* __restrict__ Tc, const float* __restrict__ Ts,
                    float* __restrict__ out) {
    __shared__ float y4[4][64];
    __shared__ float hh[4][129];
    __shared__ int   pxy[4][2];
    __shared__ float wxy[2];
    __shared__ float tc[128], ts[128];
    int b = blockIdx.x;
    if (threadIdx.x < 128) {
        tc[threadIdx.x] = Tc[threadIdx.x];
        ts[threadIdx.x] = Ts[threadIdx.x];
    }
    if (threadIdx.x == 0) {
        float Lxf = fmaxf((float)Lx[0], 1e-6f);
        float Lyf = fmaxf((float)Ly[0], 1e-6f);
        float x01 = fminf(fmaxf(xyt[b*3 + 0] / Lxf, 0.f), 1.f);
        float y01 = fminf(fmaxf(xyt[b*3 + 1] / Lyf, 0.f), 1.f);
        float gx = x01 * (NXg - 1), gy = y01 * (NYg - 1);
        int x0 = (int)floorf(gx), y0 = (int)floorf(gy);
        int x1 = min(x0 + 1, NXg - 1), y1 = min(y0 + 1, NYg - 1);
        wxy[0] = gx - (float)x0;
        wxy[1] = gy - (float)y0;
        pxy[0][0] = x0; pxy[0][1] = y0;
        pxy[1][0] = x1; pxy[1][1] = y0;
        pxy[2][0] = x0; pxy[2][1] = y1;
        pxy[3][0] = x1; pxy[3][1] = y1;
    }
    __syncthreads();
    {
        int p = threadIdx.x >> 6, o = threadIdx.x & 63;
        int px = pxy[p][0], py = pxy[p][1];
        float gkr[12], gki[12];
        #pragma unroll
        for (int ky = 0; ky < 12; ky++) { gkr[ky] = 0.f; gki[ky] = 0.f; }
        for (int kxi = 0; kxi < 24; kxi++) {
            int kx = (kxi < 12) ? kxi : (104 + kxi);
            int m = (kx * px) & 127;
            float cc = tc[m], ss = ts[m];
            #pragma unroll
            for (int ky = 0; ky < 12; ky++) {
                size_t idx = (size_t)(kxi*12 + ky)*4096 + b*64 + o;
                float a = (float)ofhr[idx], bb = (float)ofhi[idx];
                gkr[ky] += a*cc - bb*ss;
                gki[ky] += a*ss + bb*cc;
            }
        }
        float sp = gkr[0];
        #pragma unroll
        for (int ky = 1; ky < 12; ky++) {
            int m = (ky * py) & 127;
            sp += 2.f * (gkr[ky]*tc[m] - gki[ky]*ts[m]);
        }
        float s = 0.f;
        const _Float16* xb = x + ((size_t)(b*128 + px)*128 + py)*64;
        #pragma unroll 4
        for (int c = 0; c < 64; c++)
            s += pw[3*4096 + o*64 + c] * (float)xb[c];
        y4[p][o] = sp * (1.f/16384.f) + s + pwb[3*64 + o];
    }
    __syncthreads();
    for (int i = threadIdx.x; i < 512; i += 256) {
        int p = i >> 7, f = i & 127;
        float s = fc1b[f];
        #pragma unroll 4
        for (int w = 0; w < 64; w++) s += y4[p][w] * fc1w[w*128 + f];
        hh[p][f] = 0.5f * s * (1.f + erff(s * 0.70710678118654752f));
    }
    __syncthreads();
    if (threadIdx.x < 3) {
        int o3 = threadIdx.x;
        float f4[4];
        #pragma unroll
        for (int p = 0; p < 4; p++) {
            float s = fc2b[o3];
            #pragma unroll 4
            for (int f = 0; f < 128; f++) s += hh[p][f] * fc2w[f*3 + o3];
            f4[p] = s;
        }
        float wx = wxy[0], wy = wxy[1];
        float top = f4[0]*(1.f - wx) + f4[1]*wx;
        float bot = f4[2]*(1.f - wx) + f4[3]*wx;
        out[b*3 + o3] = top*(1.f - wy) + bot*wy;
    }
}

extern "C" void kernel_launch(void* const* d_in, const int* in_sizes, int n_in,
                              void* d_out, int out_size, void* d_ws, size_t ws_size,
                              hipStream_t stream) {
    const float* xyt    = (const float*)d_in[0];
    const float* obs_c  = (const float*)d_in[1];
    const float* obs_v  = (const float*)d_in[2];
    const float* xg     = (const float*)d_in[3];
    const float* yg     = (const float*)d_in[4];
    const float* fc0w   = (const float*)d_in[5];
    const float* fc0b   = (const float*)d_in[6];
    const float* w1r    = (const float*)d_in[7];
    const float* w1i    = (const float*)d_in[8];
    const float* w2r    = (const float*)d_in[9];
    const float* w2i    = (const float*)d_in[10];
    const float* pww    = (const float*)d_in[11];
    const float* pwb    = (const float*)d_in[12];
    const float* fc1w   = (const float*)d_in[13];
    const float* fc1b   = (const float*)d_in[14];
    const float* fc2w   = (const float*)d_in[15];
    const float* fc2b   = (const float*)d_in[16];
    const int*   nb     = (const int*)d_in[17];
    const int*   siy    = (const int*)d_in[18];
    const int*   six    = (const int*)d_in[19];
    const int*   Lx     = (const int*)d_in[20];
    const int*   Ly     = (const int*)d_in[21];
    float* out = (float*)d_out;

    float* W = (float*)d_ws;
    float* Tc  = W + OFF_TC;
    float* Ts  = W + OFF_TS;
    _Float16* Hbase = (_Float16*)(W + F32_END);
    _Float16* T1e_g  = Hbase + H_T1E;
    _Float16* T1eT_g = Hbase + H_T1ET;
    _Float16* A2_g   = Hbase + H_A2;
    _Float16* PWh    = Hbase + H_PWH;
    _Float16* T2eT_g = Hbase + H_T2ET;
    _Float16* xfhr   = Hbase + H_XFHR;
    _Float16* xfhi   = Hbase + H_XFHI;
    _Float16* ofhr   = Hbase + H_OFHR;
    _Float16* ofhi   = Hbase + H_OFHI;
    _Float16* Whr    = Hbase + H_WHR;
    _Float16* Whi    = Hbase + H_WHI;
    _Float16* Yg     = Hbase + H_YG;
    _Float16* xh     = Hbase + H_X;
    float*    val    = (float*)(Hbase + H_U);
    float*    cnt    = val + Bq*Pg;
    _Float16* Gh     = Hbase + H_U;   // NOTE: aliases val/cnt — but val/cnt are re-read by
                                      // k_s45(l=0), so Gh must NOT be written before that...
    // Gh is first written by k_sG (after fc0y) and k_s45(l=0) reads BOTH Gh and val/cnt.
    // Resolve: place Gh after val/cnt instead of aliasing.
    _Float16* Gh2    = Hbase + H_U + (size_t)4*Bq*Pg;   // 8 MB after val/cnt

    hipMemsetAsync(val, 0, (size_t)2 * Bq * Pg * sizeof(float), stream);

    k_prep<<<1232, 256, 0, stream>>>(T1e_g, T1eT_g, A2_g, pww, PWh, T2eT_g, Tc, Ts,
                                     xyt, obs_c, obs_v, nb, siy, six, val, cnt,
                                     w1r, w1i, w2r, w2i, Whr, Whi);
    k_fc0y<<<dim3(128, Bq), 256, 0, stream>>>(val, cnt, xg, yg, fc0w, fc0b, T1e_g, Yg);

    for (int l = 0; l < 3; l++) {
        k_sB<<<Bq*Wd, 256, 0, stream>>>(Yg, A2_g, xfhr, xfhi);
        k_s3m<<<288, 256, 0, stream>>>(xfhr, xfhi, Whr, Whi, ofhr, ofhi, l);
        k_sG<<<dim3(Bq, 24), 256, 0, stream>>>(ofhr, ofhi, T2eT_g, Gh2);
        k_s45<<<dim3(128, Bq), 256, 0, stream>>>(xh, Gh2, T1e_g, T1eT_g, PWh, pwb, Yg, l,
                                                 xyt, Lx, val, cnt, xg, yg, fc0w, fc0b);
    }
    // layer 3: spectral coefficients (MFMA path) + k_final
    k_sB<<<Bq*Wd, 256, 0, stream>>>(Yg, A2_g, xfhr, xfhi);
    k_s3m<<<288, 256, 0, stream>>>(xfhr, xfhi, Whr, Whi, ofhr, ofhi, 3);
    k_final<<<Bq, 256, 0, stream>>>(xh, ofhr, ofhi, pww, pwb, fc1w, fc1b, fc2w, fc2b,
                                    xyt, Lx, Ly, Tc, Ts, out);
}